// Round 9
// baseline (484.654 us; speedup 1.0000x reference)
//
#include <hip/hip_runtime.h>
#include <math.h>

typedef unsigned short u16;
typedef unsigned int   u32;
typedef __attribute__((ext_vector_type(8))) short bf16x8;
typedef __attribute__((ext_vector_type(4))) float f32x4;

constexpr int Tn=2048, Dm=1024, EDc=2048, Ns=16, Rr=64, NEx=8, FFc=2048;
constexpr int SCH=32, SNCH=Tn/SCH;
constexpr int MAXTM=40;          // 128-row tile map capacity (down8)
constexpr int MAXTM2=24;         // 256-row tile map capacity (gateup8)
constexpr float LOG2E = 1.44269504f;

__device__ __forceinline__ float siluf(float x){ return __fdividef(x, 1.f + __expf(-x)); }
__device__ __forceinline__ u16 bfr(float f){
  u32 u = __float_as_uint(f);
  return (u16)((u + 0x7fffu + ((u>>16)&1u)) >> 16);
}
__device__ __forceinline__ float b2f(u16 h){ return __uint_as_float(((u32)h)<<16); }

__device__ __forceinline__ void gload16(const void* g, void* l){
  __builtin_amdgcn_global_load_lds((const __attribute__((address_space(1))) void*)g,
                                   (__attribute__((address_space(3))) void*)l, 16, 0, 0);
}

// ---------------- fp32 -> bf16 bulk convert -------------------------------
__global__ __launch_bounds__(256) void f2b_k(const float* __restrict__ in,
                                             u16* __restrict__ out, int n4){
  int i = blockIdx.x*256 + threadIdx.x;
  if (i >= n4) return;
  float4 v = ((const float4*)in)[i];
  u32 lo = (u32)bfr(v.x) | ((u32)bfr(v.y)<<16);
  u32 hi = (u32)bfr(v.z) | ((u32)bfr(v.w)<<16);
  ((uint2*)out)[i] = make_uint2(lo, hi);
}

// ---- merged 3-way MoE weight convert (gate/up/down) ----------------------
__global__ __launch_bounds__(256) void f2b3_k(
    const float* __restrict__ g, const float* __restrict__ u,
    const float* __restrict__ d,
    u16* __restrict__ og, u16* __restrict__ ou, u16* __restrict__ od){
  const int BPW = (NEx*FFc*Dm/4)/256;
  int b = blockIdx.x;
  int which = b / BPW;
  int i = (b - which*BPW)*256 + threadIdx.x;
  const float* in = (which==0) ? g : (which==1) ? u : d;
  u16* out        = (which==0) ? og : (which==1) ? ou : od;
  float4 v = ((const float4*)in)[i];
  u32 lo = (u32)bfr(v.x) | ((u32)bfr(v.y)<<16);
  u32 hi = (u32)bfr(v.z) | ((u32)bfr(v.w)<<16);
  ((uint2*)out)[i] = make_uint2(lo, hi);
}

// ---------------- rmsnorm (bf16 out only) ---------------------------------
__global__ __launch_bounds__(256) void rmsnorm_k(const float* __restrict__ x,
                                                 const float* __restrict__ w,
                                                 u16* __restrict__ ob){
  int t = blockIdx.x;
  const float* xr = x + (size_t)t * Dm;
  float v[4]; float s = 0.f;
#pragma unroll
  for (int j = 0; j < 4; j++){ int d = threadIdx.x + j*256; v[j] = xr[d]; s += v[j]*v[j]; }
#pragma unroll
  for (int m = 1; m < 64; m <<= 1) s += __shfl_xor(s, m);
  __shared__ float red[4]; __shared__ float sb;
  int lane = threadIdx.x & 63, wv = threadIdx.x >> 6;
  if (lane == 0) red[wv] = s;
  __syncthreads();
  if (threadIdx.x == 0) sb = rsqrtf((red[0]+red[1]+red[2]+red[3]) * (1.f/Dm) + 1e-6f);
  __syncthreads();
  float sc = sb;
#pragma unroll
  for (int j = 0; j < 4; j++){
    int d = threadIdx.x + j*256;
    ob[(size_t)t*Dm + d] = bfr(v[j]*sc*w[d]);
  }
}

// ---- fused: out = x + sum4(P); rmsnorm(out) -> h2b bf16 + h2f fp32 -------
__global__ __launch_bounds__(256) void rms2red_k(
  const float* __restrict__ x, const float* __restrict__ P,
  const float* __restrict__ w,
  float* __restrict__ out, float* __restrict__ h2f, u16* __restrict__ h2b)
{
  int t = blockIdx.x, tid = threadIdx.x;
  const size_t S = (size_t)Tn*Dm;
  float v[4]; float s = 0.f;
#pragma unroll
  for (int j = 0; j < 4; j++){
    int d = tid + j*256;
    size_t idx = (size_t)t*Dm + d;
    float a = x[idx] + ((P[idx] + P[S+idx]) + (P[2*S+idx] + P[3*S+idx]));
    out[idx] = a; v[j] = a; s += a*a;
  }
#pragma unroll
  for (int m = 1; m < 64; m <<= 1) s += __shfl_xor(s, m);
  __shared__ float red[4]; __shared__ float sb;
  int lane = tid & 63, wv = tid >> 6;
  if (lane == 0) red[wv] = s;
  __syncthreads();
  if (tid == 0) sb = rsqrtf((red[0]+red[1]+red[2]+red[3]) * (1.f/Dm) + 1e-6f);
  __syncthreads();
  float sc = sb;
#pragma unroll
  for (int j = 0; j < 4; j++){
    int d = tid + j*256;
    float o = v[j]*sc*w[d];
    h2b[(size_t)t*Dm + d] = bfr(o);
    h2f[(size_t)t*Dm + d] = o;
  }
}

// ---- all-bf16 MFMA GEMM, 512 thr, 128x128 tile, counted-vmcnt dbuf -------
// grid: x = n-tile, y = m-tile, z = K-slice
template<int EPI, int OB>
__global__ __launch_bounds__(512) void gemm_bb(
    const u16* __restrict__ A, int lda,
    const u16* __restrict__ B, int ldb,
    void* __restrict__ Cv, int ldc,
    int M, int N, int Ksl, const float* __restrict__ aux)
{
  __shared__ u16 As[2*4096], Bs[2*4096];
  int tid = threadIdx.x, lane = tid & 63, wid = tid >> 6;
  int wr = wid >> 2, wc = wid & 3;
  int n0 = blockIdx.x * 128, m0 = blockIdx.y * 128;
  int r = tid >> 2;
  int kk = ((tid & 3) ^ (r & 3)) * 8;                 // swizzled slot (write side)
  size_t kbeg = (size_t)blockIdx.z * Ksl;
  const u16* Ag = A + (size_t)min(m0 + r, M-1)*lda + kbeg + kk;
  const u16* Bg = B + (size_t)min(n0 + r, N-1)*ldb + kbeg + kk;
  f32x4 acc[4][2] = {};
  int sw = ((lane>>4) ^ (lane&3)) * 8;                // swizzled slot (read side)
  int aoff[4], boff[2];
#pragma unroll
  for (int i = 0; i < 4; i++) aoff[i] = (wr*64 + i*16 + (lane&15))*32 + sw;
#pragma unroll
  for (int j = 0; j < 2; j++) boff[j] = (wc*32 + j*16 + (lane&15))*32 + sw;
  gload16(Ag, As + tid*8);
  gload16(Bg, Bs + tid*8);
  int NT = Ksl >> 5;
  for (int kt = 0; kt < NT; kt++){
    int cur = (kt & 1) * 4096;
    if (kt + 1 < NT){
      int nxt = 4096 - cur;
      gload16(Ag + (size_t)(kt+1)*32, As + nxt + tid*8);
      gload16(Bg + (size_t)(kt+1)*32, Bs + nxt + tid*8);
      asm volatile("s_waitcnt vmcnt(2)" ::: "memory");
    } else {
      asm volatile("s_waitcnt vmcnt(0)" ::: "memory");
    }
    __builtin_amdgcn_s_barrier();
    bf16x8 af[4], bv[2];
#pragma unroll
    for (int i = 0; i < 4; i++) af[i] = *(const bf16x8*)&As[cur + aoff[i]];
#pragma unroll
    for (int j = 0; j < 2; j++) bv[j] = *(const bf16x8*)&Bs[cur + boff[j]];
    asm volatile("s_waitcnt lgkmcnt(0)" ::: "memory");
    __builtin_amdgcn_sched_barrier(0);
    __builtin_amdgcn_s_barrier();
    __builtin_amdgcn_s_setprio(1);
#pragma unroll
    for (int i = 0; i < 4; i++)
#pragma unroll
      for (int j = 0; j < 2; j++)
        acc[i][j] = __builtin_amdgcn_mfma_f32_16x16x32_bf16(af[i], bv[j], acc[i][j], 0,0,0);
    __builtin_amdgcn_s_setprio(0);
  }
  float* Cf = (float*)Cv + (size_t)blockIdx.z * M * ldc;
  u16*   Cb = (u16*)Cv;
#pragma unroll
  for (int i = 0; i < 4; i++){
    int rbase = m0 + wr*64 + i*16 + ((lane>>4)<<2);
#pragma unroll
    for (int j = 0; j < 2; j++){
      int col = n0 + wc*32 + j*16 + (lane&15);
      if (col >= N) continue;
#pragma unroll
      for (int q = 0; q < 4; q++){
        int row = rbase + q;
        if (row >= M) continue;
        float v = acc[i][j][q];
        if (EPI == 1){ v += aux[col]; v = (v > 20.f) ? v : __logf(1.f + __expf(v)); }
        if (OB) Cb[(size_t)row*ldc + col] = bfr(v);
        else    Cf[(size_t)row*ldc + col] = v;
      }
    }
  }
}

// ------- grouped gate/up: 256x64 tile, A DIRECT-TO-REG, W staged ----------
// A-fragments (L2-hot h2b rows via bucket) load straight to VGPR each step:
// staged-through-LDS bytes drop 442->147 MB. Frags issued FIRST, weight
// stage second -> compiler's MFMA dep-wait is vmcnt(1), stage stays in
// flight. Manual vmcnt(5) (tail 4) drains only the prior-step stage.
// grid: x = n-tile (32), y = compact tile index (256-row tiles)
__global__ __launch_bounds__(512) void gateup8(
    const u16* __restrict__ Aall,
    const u16* __restrict__ Wg, const u16* __restrict__ Wu,
    const int* __restrict__ cnt, const int* __restrict__ off,
    const int* __restrict__ bucket,
    const int* __restrict__ tmap, const int* __restrict__ ntot,
    u16* __restrict__ H)
{
  if ((int)blockIdx.y >= *ntot) return;
  int v = tmap[blockIdx.y];
  int e = v >> 16, m0 = (v & 0xFFFF) * 256;
  int Me = cnt[e];
  __shared__ u16 Gs[2*2048], Us[2*2048];
  int tid = threadIdx.x, lane = tid & 63, wid = tid >> 6;
  int wr = wid >> 1, wc = wid & 1;      // 4m x 2n, wave tile 64x32
  int n0 = blockIdx.x * 64;
  int r = tid >> 2;                     // 0..127
  int kk = ((tid & 3) ^ (r & 3)) * 8;
  int rg = r & 63;                      // weight row within 64-col panel
  const u16* GUg = ((tid < 256) ? Wg : Wu) + ((size_t)e*FFc + n0 + rg)*Dm + kk;
  u16* GUsb = (tid < 256) ? (u16*)Gs : (u16*)Us;
  int g8 = (tid & 255) * 8;
  // A-direct per-lane fragment pointers (swizzle cancels: row m, k-slice lane>>4)
  const u16 *Af0, *Af1, *Af2, *Af3;
  {
    int kf = (lane >> 4) * 8;
    int c  = lane & 15;
    int r0 = bucket[e*Tn + min(m0 + wr*64 +  0 + c, Me-1)];
    int r1 = bucket[e*Tn + min(m0 + wr*64 + 16 + c, Me-1)];
    int r2 = bucket[e*Tn + min(m0 + wr*64 + 32 + c, Me-1)];
    int r3 = bucket[e*Tn + min(m0 + wr*64 + 48 + c, Me-1)];
    Af0 = Aall + (size_t)r0*Dm + kf;
    Af1 = Aall + (size_t)r1*Dm + kf;
    Af2 = Aall + (size_t)r2*Dm + kf;
    Af3 = Aall + (size_t)r3*Dm + kf;
  }
  f32x4 ag[4][2] = {}, au[4][2] = {};
  int sw = ((lane>>4) ^ (lane&3)) * 8;
  int boff[2];
#pragma unroll
  for (int j = 0; j < 2; j++) boff[j] = (wc*32 + j*16 + (lane&15))*32 + sw;
  const int NT = Dm >> 5;               // 32
  gload16(GUg, GUsb + g8);              // stage kt=0
  for (int kt = 0; kt < NT; kt++){
    int cgu = (kt & 1) * 2048;
    // A-fragments for THIS step (issue first; barrier window covers latency)
    bf16x8 af0 = *(const bf16x8*)(Af0 + (size_t)kt*32);
    bf16x8 af1 = *(const bf16x8*)(Af1 + (size_t)kt*32);
    bf16x8 af2 = *(const bf16x8*)(Af2 + (size_t)kt*32);
    bf16x8 af3 = *(const bf16x8*)(Af3 + (size_t)kt*32);
    __builtin_amdgcn_sched_barrier(0);
    if (kt + 1 < NT){
      gload16(GUg + (size_t)(kt+1)*32, GUsb + (2048 - cgu) + g8);
      asm volatile("s_waitcnt vmcnt(5)" ::: "memory");
    } else {
      asm volatile("s_waitcnt vmcnt(4)" ::: "memory");
    }
    __builtin_amdgcn_s_barrier();
    bf16x8 gf[2], uf[2];
#pragma unroll
    for (int j = 0; j < 2; j++){ gf[j] = *(const bf16x8*)&Gs[cgu + boff[j]];
                                 uf[j] = *(const bf16x8*)&Us[cgu + boff[j]]; }
    asm volatile("s_waitcnt lgkmcnt(0)" ::: "memory");
    __builtin_amdgcn_sched_barrier(0);
    __builtin_amdgcn_s_barrier();
    __builtin_amdgcn_s_setprio(1);
#pragma unroll
    for (int j = 0; j < 2; j++){
      ag[0][j] = __builtin_amdgcn_mfma_f32_16x16x32_bf16(af0, gf[j], ag[0][j], 0,0,0);
      au[0][j] = __builtin_amdgcn_mfma_f32_16x16x32_bf16(af0, uf[j], au[0][j], 0,0,0);
      ag[1][j] = __builtin_amdgcn_mfma_f32_16x16x32_bf16(af1, gf[j], ag[1][j], 0,0,0);
      au[1][j] = __builtin_amdgcn_mfma_f32_16x16x32_bf16(af1, uf[j], au[1][j], 0,0,0);
      ag[2][j] = __builtin_amdgcn_mfma_f32_16x16x32_bf16(af2, gf[j], ag[2][j], 0,0,0);
      au[2][j] = __builtin_amdgcn_mfma_f32_16x16x32_bf16(af2, uf[j], au[2][j], 0,0,0);
      ag[3][j] = __builtin_amdgcn_mfma_f32_16x16x32_bf16(af3, gf[j], ag[3][j], 0,0,0);
      au[3][j] = __builtin_amdgcn_mfma_f32_16x16x32_bf16(af3, uf[j], au[3][j], 0,0,0);
    }
    __builtin_amdgcn_s_setprio(0);
  }
  int offe = off[e];
#pragma unroll
  for (int i = 0; i < 4; i++){
    int mb = m0 + wr*64 + i*16 + ((lane>>4)<<2);
#pragma unroll
    for (int j = 0; j < 2; j++){
      int col = n0 + wc*32 + j*16 + (lane&15);
#pragma unroll
      for (int q = 0; q < 4; q++){
        int m = mb + q;
        if (m >= Me) continue;
        float g = ag[i][j][q], u = au[i][j][q];
        H[(size_t)(offe + m)*FFc + col] = bfr(siluf(g)*u);
      }
    }
  }
}

// ------------- grouped down: 128x128, A DIRECT-TO-REG, Wd staged ----------
// grid: x = n-tile (8), y = compact 128-row tile index, z = K-half
__global__ __launch_bounds__(512) void down8(
    const u16* __restrict__ Hall, const u16* __restrict__ Wd,
    const int* __restrict__ cnt, const int* __restrict__ off,
    const int* __restrict__ tmap2, const int* __restrict__ ntot2,
    u16* __restrict__ Y)
{
  if ((int)blockIdx.y >= *ntot2) return;
  int v = tmap2[blockIdx.y];
  int e = v >> 16, m0 = (v & 0xFFFF) * 128;
  int Me = cnt[e];
  int offe = off[e];
  int kbeg = blockIdx.z * (FFc/2);
  const u16* A = Hall + (size_t)offe*FFc;
  const u16* B = Wd + (size_t)e*Dm*FFc;
  u16* C = Y + (size_t)blockIdx.z*(2*Tn)*Dm + (size_t)offe*Dm;
  __shared__ u16 Bs[2*4096];
  int tid = threadIdx.x, lane = tid & 63, wid = tid >> 6;
  int wr = wid >> 2, wc = wid & 3;
  int n0 = blockIdx.x * 128;
  int r = tid >> 2;
  int kk = ((tid & 3) ^ (r & 3)) * 8;
  const u16* Bg = B + (size_t)(n0 + r)*FFc + kbeg + kk;
  // A-direct per-lane fragment pointers (contiguous hmoe rows)
  const u16 *Af0, *Af1, *Af2, *Af3;
  {
    int kf = (lane >> 4) * 8;
    int c  = lane & 15;
    Af0 = A + (size_t)min(m0 + wr*64 +  0 + c, Me-1)*FFc + kbeg + kf;
    Af1 = A + (size_t)min(m0 + wr*64 + 16 + c, Me-1)*FFc + kbeg + kf;
    Af2 = A + (size_t)min(m0 + wr*64 + 32 + c, Me-1)*FFc + kbeg + kf;
    Af3 = A + (size_t)min(m0 + wr*64 + 48 + c, Me-1)*FFc + kbeg + kf;
  }
  f32x4 acc[4][2] = {};
  int sw = ((lane>>4) ^ (lane&3)) * 8;
  int boff[2];
#pragma unroll
  for (int j = 0; j < 2; j++) boff[j] = (wc*32 + j*16 + (lane&15))*32 + sw;
  const int NT = (FFc/2) >> 5;          // 16
  gload16(Bg, Bs + tid*8);              // stage kt=0
  for (int kt = 0; kt < NT; kt++){
    int cur = (kt & 1) * 4096;
    bf16x8 af0 = *(const bf16x8*)(Af0 + (size_t)kt*32);
    bf16x8 af1 = *(const bf16x8*)(Af1 + (size_t)kt*32);
    bf16x8 af2 = *(const bf16x8*)(Af2 + (size_t)kt*32);
    bf16x8 af3 = *(const bf16x8*)(Af3 + (size_t)kt*32);
    __builtin_amdgcn_sched_barrier(0);
    if (kt + 1 < NT){
      gload16(Bg + (size_t)(kt+1)*32, Bs + (4096 - cur) + tid*8);
      asm volatile("s_waitcnt vmcnt(5)" ::: "memory");
    } else {
      asm volatile("s_waitcnt vmcnt(4)" ::: "memory");
    }
    __builtin_amdgcn_s_barrier();
    bf16x8 bv[2];
#pragma unroll
    for (int j = 0; j < 2; j++) bv[j] = *(const bf16x8*)&Bs[cur + boff[j]];
    asm volatile("s_waitcnt lgkmcnt(0)" ::: "memory");
    __builtin_amdgcn_sched_barrier(0);
    __builtin_amdgcn_s_barrier();
    __builtin_amdgcn_s_setprio(1);
#pragma unroll
    for (int j = 0; j < 2; j++){
      acc[0][j] = __builtin_amdgcn_mfma_f32_16x16x32_bf16(af0, bv[j], acc[0][j], 0,0,0);
      acc[1][j] = __builtin_amdgcn_mfma_f32_16x16x32_bf16(af1, bv[j], acc[1][j], 0,0,0);
      acc[2][j] = __builtin_amdgcn_mfma_f32_16x16x32_bf16(af2, bv[j], acc[2][j], 0,0,0);
      acc[3][j] = __builtin_amdgcn_mfma_f32_16x16x32_bf16(af3, bv[j], acc[3][j], 0,0,0);
    }
    __builtin_amdgcn_s_setprio(0);
  }
#pragma unroll
  for (int i = 0; i < 4; i++){
    int mb = m0 + wr*64 + i*16 + ((lane>>4)<<2);
#pragma unroll
    for (int j = 0; j < 2; j++){
      int col = n0 + wc*32 + j*16 + (lane&15);
#pragma unroll
      for (int q = 0; q < 4; q++){
        int m = mb + q;
        if (m >= Me) continue;
        C[(size_t)m*Dm + col] = bfr(acc[i][j][q]);
      }
    }
  }
}

// -------- depthwise causal conv (K=4) + bias + silu; bf16 in/out ----------
__global__ __launch_bounds__(256) void conv_k(const u16* __restrict__ xzb,
    const float* __restrict__ cw, const float* __restrict__ cb,
    u16* __restrict__ xc)
{
  int idx = blockIdx.x*256 + threadIdx.x;
  int t = idx >> 11, e = idx & (EDc - 1);
  float v = cb[e];
#pragma unroll
  for (int k = 0; k < 4; k++){
    int tt = t - 3 + k;
    if (tt >= 0) v += b2f(xzb[(size_t)tt*(2*EDc) + e]) * cw[e*4 + k];
  }
  xc[(size_t)t*EDc + e] = bfr(siluf(v));
}

// ---------- reduce 4 K-slices of xp, emit xp fp32 + dtA bf16 --------------
__global__ __launch_bounds__(256) void xp_red(const float* __restrict__ part,
                                              float* __restrict__ xp,
                                              u16* __restrict__ dtA){
  int i = blockIdx.x*256 + threadIdx.x;
  const int S = Tn*96;
  float v = part[i] + part[S + i] + part[2*S + i] + part[3*S + i];
  xp[i] = v;
  int t = i / 96, c = i - t*96;
  if (c < Rr) dtA[t*Rr + c] = bfr(v);
}

// ====================== SCAN: n-in-register version =======================
__global__ __launch_bounds__(256) void scan_p1(
  const u16* __restrict__ delta, const u16* __restrict__ xc,
  const float* __restrict__ xp,  const float* __restrict__ A_log,
  float* __restrict__ hend, float* __restrict__ dsum)
{
  __shared__ u16 sdel[SCH*256], sxc[SCH*256];
  __shared__ float sB[SCH*16];
  int tid = threadIdx.x;
  int e0 = blockIdx.x*256, c = blockIdx.y, t0 = c*SCH;
#pragma unroll
  for (int i = 0; i < 4; i++){
    int f = (i*256+tid)*8;
    int t = f >> 8, e = f & 255;
    gload16(&delta[(size_t)(t0+t)*EDc + e0 + e], sdel + f);
    gload16(&xc  [(size_t)(t0+t)*EDc + e0 + e], sxc + f);
  }
  sB[tid]       = xp[(size_t)(t0 + (tid>>4))*96 + Rr + (tid&15)];
  sB[tid+256]   = xp[(size_t)(t0 + ((tid+256)>>4))*96 + Rr + (tid&15)];
  float a2[16];
  {
    const float* ar = &A_log[(size_t)(e0+tid)*16];
#pragma unroll
    for (int n = 0; n < 16; n++) a2[n] = -__expf(ar[n]) * LOG2E;
  }
  __syncthreads();
  float h[16] = {};
  float ds = 0.f;
  for (int t = 0; t < SCH; t++){
    float del = b2f(sdel[t*256 + tid]);
    float xv  = b2f(sxc [t*256 + tid]);
    ds += del;
    float dbx = del * xv;
    float4 b0 = *(const float4*)&sB[t*16];
    float4 b1 = *(const float4*)&sB[t*16+4];
    float4 b2 = *(const float4*)&sB[t*16+8];
    float4 b3 = *(const float4*)&sB[t*16+12];
    float bb[16] = {b0.x,b0.y,b0.z,b0.w, b1.x,b1.y,b1.z,b1.w,
                    b2.x,b2.y,b2.z,b2.w, b3.x,b3.y,b3.z,b3.w};
#pragma unroll
    for (int n = 0; n < 16; n++){
      float dA = exp2f(del * a2[n]);
      h[n] = fmaf(dA, h[n], dbx * bb[n]);
    }
  }
  float* hp = &hend[((size_t)c*EDc + e0 + tid)*16];
#pragma unroll
  for (int n = 0; n < 16; n += 4)
    *(float4*)&hp[n] = make_float4(h[n], h[n+1], h[n+2], h[n+3]);
  dsum[c*EDc + e0 + tid] = ds;
}

__global__ __launch_bounds__(256) void scan_p2(
  const float* __restrict__ hend, const float* __restrict__ dsum,
  const float* __restrict__ A_log, float* __restrict__ hin)
{
  int g = blockIdx.x*256 + threadIdx.x;
  int e = g >> 4;
  float a2 = -__expf(A_log[g]) * LOG2E;
  float h = 0.f;
  for (int c = 0; c < SNCH; c++){
    hin[(size_t)c*EDc*Ns + g] = h;
    float P = exp2f(a2 * dsum[c*EDc + e]);
    h = fmaf(P, h, hend[(size_t)c*EDc*Ns + g]);
  }
}

__global__ __launch_bounds__(256) void scan_p3(
  const u16* __restrict__ delta, const u16* __restrict__ xc,
  const float* __restrict__ xp,  const u16* __restrict__ xzb,
  const float* __restrict__ A_log, const float* __restrict__ D_skip,
  const float* __restrict__ hin,   u16* __restrict__ y2)
{
  __shared__ u16 sdel[SCH*256], sxc[SCH*256], sz[SCH*256];
  __shared__ float sB[SCH*16], sC[SCH*16];
  int tid = threadIdx.x;
  int e0 = blockIdx.x*256, c = blockIdx.y, t0 = c*SCH;
#pragma unroll
  for (int i = 0; i < 4; i++){
    int f = (i*256+tid)*8;
    int t = f >> 8, e = f & 255;
    gload16(&delta[(size_t)(t0+t)*EDc + e0 + e], sdel + f);
    gload16(&xc  [(size_t)(t0+t)*EDc + e0 + e], sxc + f);
    gload16(&xzb [(size_t)(t0+t)*(2*EDc) + EDc + e0 + e], sz + f);
  }
  {
    int f0 = tid, f1 = tid + 256;
    sB[f0] = xp[(size_t)(t0 + (f0>>4))*96 + Rr + (f0&15)];
    sB[f1] = xp[(size_t)(t0 + (f1>>4))*96 + Rr + (f1&15)];
    sC[f0] = xp[(size_t)(t0 + (f0>>4))*96 + Rr + Ns + (f0&15)];
    sC[f1] = xp[(size_t)(t0 + (f1>>4))*96 + Rr + Ns + (f1&15)];
  }
  float a2[16];
  {
    const float* ar = &A_log[(size_t)(e0+tid)*16];
#pragma unroll
    for (int n = 0; n < 16; n++) a2[n] = -__expf(ar[n]) * LOG2E;
  }
  float dsk = D_skip[e0 + tid];
  float h[16];
  {
    const float* hp = &hin[((size_t)c*EDc + e0 + tid)*16];
#pragma unroll
    for (int n = 0; n < 16; n += 4){
      float4 hv = *(const float4*)&hp[n];
      h[n] = hv.x; h[n+1] = hv.y; h[n+2] = hv.z; h[n+3] = hv.w;
    }
  }
  __syncthreads();
  for (int t = 0; t < SCH; t++){
    float del = b2f(sdel[t*256 + tid]);
    float xv  = b2f(sxc [t*256 + tid]);
    float zv  = b2f(sz  [t*256 + tid]);
    float dbx = del * xv;
    float4 b0 = *(const float4*)&sB[t*16];
    float4 b1 = *(const float4*)&sB[t*16+4];
    float4 b2 = *(const float4*)&sB[t*16+8];
    float4 b3 = *(const float4*)&sB[t*16+12];
    float bb[16] = {b0.x,b0.y,b0.z,b0.w, b1.x,b1.y,b1.z,b1.w,
                    b2.x,b2.y,b2.z,b2.w, b3.x,b3.y,b3.z,b3.w};
    float4 c0 = *(const float4*)&sC[t*16];
    float4 c1 = *(const float4*)&sC[t*16+4];
    float4 c2 = *(const float4*)&sC[t*16+8];
    float4 c3 = *(const float4*)&sC[t*16+12];
    float cc[16] = {c0.x,c0.y,c0.z,c0.w, c1.x,c1.y,c1.z,c1.w,
                    c2.x,c2.y,c2.z,c2.w, c3.x,c3.y,c3.z,c3.w};
    float p0 = 0.f, p1 = 0.f, p2 = 0.f, p3 = 0.f;
#pragma unroll
    for (int n = 0; n < 16; n += 4){
      float dA0 = exp2f(del * a2[n]);
      float dA1 = exp2f(del * a2[n+1]);
      float dA2 = exp2f(del * a2[n+2]);
      float dA3 = exp2f(del * a2[n+3]);
      h[n]   = fmaf(dA0, h[n],   dbx * bb[n]);
      h[n+1] = fmaf(dA1, h[n+1], dbx * bb[n+1]);
      h[n+2] = fmaf(dA2, h[n+2], dbx * bb[n+2]);
      h[n+3] = fmaf(dA3, h[n+3], dbx * bb[n+3]);
      p0 = fmaf(h[n],   cc[n],   p0);
      p1 = fmaf(h[n+1], cc[n+1], p1);
      p2 = fmaf(h[n+2], cc[n+2], p2);
      p3 = fmaf(h[n+3], cc[n+3], p3);
    }
    float p = (p0 + p1) + (p2 + p3);
    y2[(size_t)(t0+t)*EDc + e0 + tid] = bfr((p + dsk*xv) * siluf(zv));
  }
}

// ------------- router ------------------------------------------------------
__global__ __launch_bounds__(256) void route_k(
  const float* __restrict__ h2, const float* __restrict__ Wr,
  float* __restrict__ logits_out,
  int* __restrict__ cnt, int* __restrict__ bucket,
  int* __restrict__ tok_e, int* __restrict__ tok_idx, float* __restrict__ tok_w)
{
  int t = blockIdx.x, tid = threadIdx.x;
  float p[8] = {};
#pragma unroll
  for (int j = 0; j < 4; j++){
    int d = tid + j*256;
    float xv = h2[(size_t)t*Dm + d];
#pragma unroll
    for (int e = 0; e < 8; e++) p[e] += xv * Wr[e*Dm + d];
  }
#pragma unroll
  for (int e = 0; e < 8; e++)
#pragma unroll
    for (int m = 1; m < 64; m <<= 1) p[e] += __shfl_xor(p[e], m);
  __shared__ float part[4][8];
  __shared__ float lg[8];
  int lane = tid & 63, wv = tid >> 6;
  if (lane == 0)
#pragma unroll
    for (int e = 0; e < 8; e++) part[wv][e] = p[e];
  __syncthreads();
  if (tid < 8){
    float v = part[0][tid]+part[1][tid]+part[2][tid]+part[3][tid];
    lg[tid] = v;
    logits_out[(size_t)t*8 + tid] = v;
  }
  __syncthreads();
  if (tid == 0){
    float mx = lg[0];
#pragma unroll
    for (int e = 1; e < 8; e++) mx = fmaxf(mx, lg[e]);
    float ex[8], s = 0.f;
#pragma unroll
    for (int e = 0; e < 8; e++){ ex[e] = expf(lg[e] - mx); s += ex[e]; }
    float inv = 1.f / s;
    int i0 = 0; float b0 = ex[0]*inv;
#pragma unroll
    for (int e = 1; e < 8; e++){ float pe = ex[e]*inv; if (pe > b0){ b0 = pe; i0 = e; } }
    int i1 = -1; float b1 = -1e30f;
#pragma unroll
    for (int e = 0; e < 8; e++){ if (e == i0) continue; float pe = ex[e]*inv; if (pe > b1){ b1 = pe; i1 = e; } }
    int k0 = atomicAdd(&cnt[i0], 1); bucket[i0*Tn + k0] = t;
    int k1 = atomicAdd(&cnt[i1], 1); bucket[i1*Tn + k1] = t;
    tok_e[2*t] = i0;   tok_idx[2*t] = k0;   tok_w[2*t] = b0;
    tok_e[2*t+1] = i1; tok_idx[2*t+1] = k1; tok_w[2*t+1] = b1;
  }
}

// ---------- offsets + dual compact tile maps (256-row and 128-row) --------
__global__ void prefix_k(const int* __restrict__ cnt, int* __restrict__ off,
                         int* __restrict__ tmap, int* __restrict__ ntot,
                         int* __restrict__ tmap2, int* __restrict__ ntot2){
  if (threadIdx.x == 0 && blockIdx.x == 0){
    int s = 0;
    for (int e = 0; e < NEx; e++){ off[e] = s; s += cnt[e]; }
    int nt = 0;
    for (int e = 0; e < NEx; e++){
      int tiles = (cnt[e] + 255) >> 8;
      for (int tm = 0; tm < tiles; tm++) tmap[nt++] = (e << 16) | tm;
    }
    *ntot = nt;
    int n2 = 0;
    for (int e = 0; e < NEx; e++){
      int tiles = (cnt[e] + 127) >> 7;
      for (int tm = 0; tm < tiles; tm++) tmap2[n2++] = (e << 16) | tm;
    }
    *ntot2 = n2;
  }
}

// ---------------- final combine (2 bf16 K-split slabs) --------------------
__global__ __launch_bounds__(256) void combine_k(float* __restrict__ out,
    const u16* __restrict__ Y, const int* __restrict__ off,
    const int* __restrict__ tok_e, const int* __restrict__ tok_idx,
    const float* __restrict__ tok_w)
{
  int t = blockIdx.x, tid = threadIdx.x;
  const size_t S2 = (size_t)(2*Tn)*Dm;
  int e0 = tok_e[2*t],   e1 = tok_e[2*t+1];
  size_t r0 = (size_t)(off[e0] + tok_idx[2*t])*Dm;
  size_t r1 = (size_t)(off[e1] + tok_idx[2*t+1])*Dm;
  float w0 = tok_w[2*t], w1 = tok_w[2*t+1];
#pragma unroll
  for (int j = 0; j < 4; j++){
    int d = tid + j*256;
    float y0 = b2f(Y[r0 + d]) + b2f(Y[S2 + r0 + d]);
    float y1 = b2f(Y[r1 + d]) + b2f(Y[S2 + r1 + d]);
    out[(size_t)t*Dm + d] += w0*y0 + w1*y1;
  }
}

extern "C" void kernel_launch(void* const* d_in, const int* in_sizes, int n_in,
                              void* d_out, int out_size, void* d_ws, size_t ws_size,
                              hipStream_t stream) {
  const float* x      = (const float*)d_in[0];
  const float* rms1_w = (const float*)d_in[1];
  const float* rms2_w = (const float*)d_in[2];
  const float* W_in   = (const float*)d_in[3];
  const float* conv_w = (const float*)d_in[4];
  const float* conv_b = (const float*)d_in[5];
  const float* W_xprj = (const float*)d_in[6];
  const float* W_dt   = (const float*)d_in[7];
  const float* b_dt   = (const float*)d_in[8];
  const float* A_log  = (const float*)d_in[9];
  const float* D_skip = (const float*)d_in[10];
  const float* W_out  = (const float*)d_in[11];
  const float* W_rt   = (const float*)d_in[12];
  const float* gate_w = (const float*)d_in[13];
  const float* up_w   = (const float*)d_in[14];
  const float* down_w = (const float*)d_in[15];

  float* out        = (float*)d_out;
  float* logits_out = out + (size_t)Tn*Dm;

  uint8_t* base = (uint8_t*)d_ws;
  size_t o = 0;
  auto alloc = [&](size_t bytes) -> void* {
    void* p = base + o;
    o = (o + bytes + 255) & ~(size_t)255;
    return p;
  };
  // ---- survivors (live through MoE phase) ----
  float* h2f   = (float*)alloc((size_t)Tn*Dm*4);
  u16*   h2b   = (u16*)  alloc((size_t)Tn*Dm*2);
  u16*   hmoe  = (u16*)  alloc((size_t)2*Tn*FFc*2);
  u16*   yslot = (u16*)  alloc((size_t)2*(2*Tn)*Dm*2);
  int*   cnt     = (int*)alloc(64);
  int*   off     = (int*)alloc(64);
  int*   ntot    = (int*)alloc(64);
  int*   ntot2   = (int*)alloc(64);
  int*   tmap    = (int*)alloc(MAXTM2*4 + 192);
  int*   tmap2   = (int*)alloc(MAXTM*4 + 192);
  int*   bucket  = (int*)alloc((size_t)NEx*Tn*4);
  int*   tok_e   = (int*)alloc((size_t)2*Tn*4);
  int*   tok_idx = (int*)alloc((size_t)2*Tn*4);
  float* tok_w   = (float*)alloc((size_t)2*Tn*4);
  // ---- overlap zone: mamba-phase buffers also host bf16 MoE weights ----
  size_t oz = o;
  u16*   xzb   = (u16*)  alloc((size_t)Tn*2*EDc*2);
  u16*   delta = (u16*)  alloc((size_t)Tn*EDc*2);
  u16*   xc    = (u16*)  alloc((size_t)Tn*EDc*2);
  u16*   y2    = (u16*)  alloc((size_t)Tn*EDc*2);
  u16*   h1b   = (u16*)  alloc((size_t)Tn*Dm*2);
  u16*   dtA   = (u16*)  alloc((size_t)Tn*Rr*2);
  float* xp    = (float*)alloc((size_t)Tn*96*4);
  float* xp_part=(float*)alloc((size_t)4*Tn*96*4);
  float* hend  = (float*)alloc((size_t)SNCH*EDc*Ns*4);
  float* hin   = (float*)alloc((size_t)SNCH*EDc*Ns*4);
  float* dsum  = (float*)alloc((size_t)SNCH*EDc*4);
  // W_out K-split partials alias over xzb+delta+xc (dead by then)
  float* wpart = (float*)xzb;
  // MoE bf16 weights overlay the dead mamba buffers
  u16* wgate = (u16*)(base + oz);
  u16* wup   = wgate + (size_t)NEx*FFc*Dm;
  u16* wdown = wup   + (size_t)NEx*FFc*Dm;
  // mamba bf16 weights overlay the dead-until-MoE survivors
  u16* wbin  = (u16*)yslot;
  u16* wbout = wbin + (size_t)2*EDc*Dm;
  u16* wxp   = (u16*)hmoe;
  u16* wdt   = wxp + (size_t)96*EDc;

  // 0) convert mamba weights to bf16
  f2b_k<<<(2*EDc*Dm/4)/256, 256, 0, stream>>>(W_in,   wbin,  2*EDc*Dm/4);
  f2b_k<<<(Dm*EDc/4)/256,   256, 0, stream>>>(W_out,  wbout, Dm*EDc/4);
  f2b_k<<<(96*EDc/4)/256,   256, 0, stream>>>(W_xprj, wxp,   96*EDc/4);
  f2b_k<<<(EDc*Rr/4)/256,   256, 0, stream>>>(W_dt,   wdt,   EDc*Rr/4);
  // 1) rmsnorm 1 -> h1b
  rmsnorm_k<<<Tn, 256, 0, stream>>>(x, rms1_w, h1b);
  // 2) xz = h1 @ W_in^T -> bf16  (grid x=n-tiles, y=m-tiles)
  gemm_bb<0,1><<<dim3(32,16,1), 512, 0, stream>>>(h1b, Dm, wbin, Dm, xzb, 2*EDc, Tn, 2*EDc, Dm, nullptr);
  // 3) conv + silu -> xc
  conv_k<<<(Tn*EDc)/256, 256, 0, stream>>>(xzb, conv_w, conv_b, xc);
  // 4) xp = xc @ W_xproj^T, K-split x4, then reduce (+ dtA)
  gemm_bb<0,0><<<dim3(1,16,4), 512, 0, stream>>>(xc, EDc, wxp, EDc, xp_part, 96, Tn, 96, EDc/4, nullptr);
  xp_red<<<(Tn*96)/256, 256, 0, stream>>>(xp_part, xp, dtA);
  // 5) delta = softplus(dtA @ W_dt^T + b_dt) -> bf16
  gemm_bb<1,1><<<dim3(16,16,1), 512, 0, stream>>>(dtA, Rr, wdt, Rr, delta, EDc, Tn, EDc, Rr, b_dt);
  // 6) chunked parallel scan -> y2
  scan_p1<<<dim3(EDc/256, SNCH), 256, 0, stream>>>(delta, xc, xp, A_log, hend, dsum);
  scan_p2<<<EDc*Ns/256, 256, 0, stream>>>(hend, dsum, A_log, hin);
  scan_p3<<<dim3(EDc/256, SNCH), 256, 0, stream>>>(delta, xc, xp, xzb, A_log, D_skip, hin, y2);
  // 7) y2 @ W_out^T, K-split x4 -> fp32 partials
  gemm_bb<0,0><<<dim3(8,16,4), 512, 0, stream>>>(y2, EDc, wbout, EDc, wpart, Dm, Tn, Dm, EDc/4, nullptr);
  // 8) fused: out = x + sum(partials); rmsnorm -> h2b + h2f
  rms2red_k<<<Tn, 256, 0, stream>>>(x, wpart, rms2_w, out, h2f, h2b);
  // 9) MoE weights -> bf16 (overlay zone), merged single launch
  f2b3_k<<<3*((NEx*FFc*Dm/4)/256), 256, 0, stream>>>(gate_w, up_w, down_w, wgate, wup, wdown);
  // 10) routing
  hipMemsetAsync(cnt, 0, 32, stream);
  route_k<<<Tn, 256, 0, stream>>>(h2f, W_rt, logits_out, cnt, bucket, tok_e, tok_idx, tok_w);
  prefix_k<<<1, 64, 0, stream>>>(cnt, off, tmap, ntot, tmap2, ntot2);
  // 11) expert gate/up, 256x64 tiles, A direct-to-reg (only W staged in LDS)
  gateup8<<<dim3(32, MAXTM2), 512, 0, stream>>>(h2b, wgate, wup, cnt, off, bucket, tmap, ntot, hmoe);
  // 12) expert down, 128x128 tiles, A direct-to-reg, K-split x2
  down8<<<dim3(8, MAXTM, 2), 512, 0, stream>>>(hmoe, wdown, cnt, off, tmap2, ntot2, yslot);
  // 13) combine
  combine_k<<<Tn, 256, 0, stream>>>(out, yslot, off, tok_e, tok_idx, tok_w);
}

// Round 10
// 384.317 us; speedup vs baseline: 1.2611x; 1.2611x over previous
//
#include <hip/hip_runtime.h>
#include <math.h>

typedef unsigned short u16;
typedef unsigned int   u32;
typedef __attribute__((ext_vector_type(8))) short bf16x8;
typedef __attribute__((ext_vector_type(4))) float f32x4;

constexpr int Tn=2048, Dm=1024, EDc=2048, Ns=16, Rr=64, NEx=8, FFc=2048;
constexpr int SCH=32, SNCH=Tn/SCH;
constexpr int MAXTM=40;
constexpr float LOG2E = 1.44269504f;

__device__ __forceinline__ float siluf(float x){ return __fdividef(x, 1.f + __expf(-x)); }
__device__ __forceinline__ u16 bfr(float f){
  u32 u = __float_as_uint(f);
  return (u16)((u + 0x7fffu + ((u>>16)&1u)) >> 16);
}
__device__ __forceinline__ float b2f(u16 h){ return __uint_as_float(((u32)h)<<16); }

__device__ __forceinline__ void gload16(const void* g, void* l){
  __builtin_amdgcn_global_load_lds((const __attribute__((address_space(1))) void*)g,
                                   (__attribute__((address_space(3))) void*)l, 16, 0, 0);
}

// ---- merged 4-way mamba weight convert (W_in, W_out, W_xproj, W_dt) ------
__global__ __launch_bounds__(256) void f2bm_k(
    const float* __restrict__ i0, u16* __restrict__ o0, int n0,
    const float* __restrict__ i1, u16* __restrict__ o1, int n1,
    const float* __restrict__ i2, u16* __restrict__ o2, int n2,
    const float* __restrict__ i3, u16* __restrict__ o3, int n3)
{
  int i = blockIdx.x*256 + threadIdx.x;
  const float* in; u16* out;
  if (i < n0){ in = i0; out = o0; }
  else if ((i -= n0) < n1){ in = i1; out = o1; }
  else if ((i -= n1) < n2){ in = i2; out = o2; }
  else if ((i -= n2) < n3){ in = i3; out = o3; }
  else return;
  float4 v = ((const float4*)in)[i];
  u32 lo = (u32)bfr(v.x) | ((u32)bfr(v.y)<<16);
  u32 hi = (u32)bfr(v.z) | ((u32)bfr(v.w)<<16);
  ((uint2*)out)[i] = make_uint2(lo, hi);
}

// ---- merged 3-way MoE weight convert (gate/up/down) ----------------------
__global__ __launch_bounds__(256) void f2b3_k(
    const float* __restrict__ g, const float* __restrict__ u,
    const float* __restrict__ d,
    u16* __restrict__ og, u16* __restrict__ ou, u16* __restrict__ od){
  const int BPW = (NEx*FFc*Dm/4)/256;
  int b = blockIdx.x;
  int which = b / BPW;
  int i = (b - which*BPW)*256 + threadIdx.x;
  const float* in = (which==0) ? g : (which==1) ? u : d;
  u16* out        = (which==0) ? og : (which==1) ? ou : od;
  float4 v = ((const float4*)in)[i];
  u32 lo = (u32)bfr(v.x) | ((u32)bfr(v.y)<<16);
  u32 hi = (u32)bfr(v.z) | ((u32)bfr(v.w)<<16);
  ((uint2*)out)[i] = make_uint2(lo, hi);
}

// ---------------- rmsnorm (bf16 out only) ---------------------------------
__global__ __launch_bounds__(256) void rmsnorm_k(const float* __restrict__ x,
                                                 const float* __restrict__ w,
                                                 u16* __restrict__ ob){
  int t = blockIdx.x;
  const float* xr = x + (size_t)t * Dm;
  float v[4]; float s = 0.f;
#pragma unroll
  for (int j = 0; j < 4; j++){ int d = threadIdx.x + j*256; v[j] = xr[d]; s += v[j]*v[j]; }
#pragma unroll
  for (int m = 1; m < 64; m <<= 1) s += __shfl_xor(s, m);
  __shared__ float red[4]; __shared__ float sb;
  int lane = threadIdx.x & 63, wv = threadIdx.x >> 6;
  if (lane == 0) red[wv] = s;
  __syncthreads();
  if (threadIdx.x == 0) sb = rsqrtf((red[0]+red[1]+red[2]+red[3]) * (1.f/Dm) + 1e-6f);
  __syncthreads();
  float sc = sb;
#pragma unroll
  for (int j = 0; j < 4; j++){
    int d = threadIdx.x + j*256;
    ob[(size_t)t*Dm + d] = bfr(v[j]*sc*w[d]);
  }
}

// ---- fused: out = x + sum4(P); rmsnorm(out) -> h2b bf16 + h2f fp32 -------
__global__ __launch_bounds__(256) void rms2red_k(
  const float* __restrict__ x, const float* __restrict__ P,
  const float* __restrict__ w,
  float* __restrict__ out, float* __restrict__ h2f, u16* __restrict__ h2b)
{
  int t = blockIdx.x, tid = threadIdx.x;
  const size_t S = (size_t)Tn*Dm;
  float v[4]; float s = 0.f;
#pragma unroll
  for (int j = 0; j < 4; j++){
    int d = tid + j*256;
    size_t idx = (size_t)t*Dm + d;
    float a = x[idx] + ((P[idx] + P[S+idx]) + (P[2*S+idx] + P[3*S+idx]));
    out[idx] = a; v[j] = a; s += a*a;
  }
#pragma unroll
  for (int m = 1; m < 64; m <<= 1) s += __shfl_xor(s, m);
  __shared__ float red[4]; __shared__ float sb;
  int lane = tid & 63, wv = tid >> 6;
  if (lane == 0) red[wv] = s;
  __syncthreads();
  if (tid == 0) sb = rsqrtf((red[0]+red[1]+red[2]+red[3]) * (1.f/Dm) + 1e-6f);
  __syncthreads();
  float sc = sb;
#pragma unroll
  for (int j = 0; j < 4; j++){
    int d = tid + j*256;
    float o = v[j]*sc*w[d];
    h2b[(size_t)t*Dm + d] = bfr(o);
    h2f[(size_t)t*Dm + d] = o;
  }
}

// ---- all-bf16 MFMA GEMM, 512 thr, 128x128 tile, counted-vmcnt dbuf -------
// grid: x = n-tile, y = m-tile, z = K-slice
template<int EPI, int OB>
__global__ __launch_bounds__(512) void gemm_bb(
    const u16* __restrict__ A, int lda,
    const u16* __restrict__ B, int ldb,
    void* __restrict__ Cv, int ldc,
    int M, int N, int Ksl, const float* __restrict__ aux)
{
  __shared__ u16 As[2*4096], Bs[2*4096];
  int tid = threadIdx.x, lane = tid & 63, wid = tid >> 6;
  int wr = wid >> 2, wc = wid & 3;
  int n0 = blockIdx.x * 128, m0 = blockIdx.y * 128;
  int r = tid >> 2;
  int kk = ((tid & 3) ^ (r & 3)) * 8;                 // swizzled slot (write side)
  size_t kbeg = (size_t)blockIdx.z * Ksl;
  const u16* Ag = A + (size_t)min(m0 + r, M-1)*lda + kbeg + kk;
  const u16* Bg = B + (size_t)min(n0 + r, N-1)*ldb + kbeg + kk;
  f32x4 acc[4][2] = {};
  int sw = ((lane>>4) ^ (lane&3)) * 8;                // swizzled slot (read side)
  int aoff[4], boff[2];
#pragma unroll
  for (int i = 0; i < 4; i++) aoff[i] = (wr*64 + i*16 + (lane&15))*32 + sw;
#pragma unroll
  for (int j = 0; j < 2; j++) boff[j] = (wc*32 + j*16 + (lane&15))*32 + sw;
  gload16(Ag, As + tid*8);
  gload16(Bg, Bs + tid*8);
  int NT = Ksl >> 5;
  for (int kt = 0; kt < NT; kt++){
    int cur = (kt & 1) * 4096;
    if (kt + 1 < NT){
      int nxt = 4096 - cur;
      gload16(Ag + (size_t)(kt+1)*32, As + nxt + tid*8);
      gload16(Bg + (size_t)(kt+1)*32, Bs + nxt + tid*8);
      asm volatile("s_waitcnt vmcnt(2)" ::: "memory");
    } else {
      asm volatile("s_waitcnt vmcnt(0)" ::: "memory");
    }
    __builtin_amdgcn_s_barrier();
    bf16x8 af[4], bv[2];
#pragma unroll
    for (int i = 0; i < 4; i++) af[i] = *(const bf16x8*)&As[cur + aoff[i]];
#pragma unroll
    for (int j = 0; j < 2; j++) bv[j] = *(const bf16x8*)&Bs[cur + boff[j]];
    asm volatile("s_waitcnt lgkmcnt(0)" ::: "memory");
    __builtin_amdgcn_sched_barrier(0);
    __builtin_amdgcn_s_barrier();
    __builtin_amdgcn_s_setprio(1);
#pragma unroll
    for (int i = 0; i < 4; i++)
#pragma unroll
      for (int j = 0; j < 2; j++)
        acc[i][j] = __builtin_amdgcn_mfma_f32_16x16x32_bf16(af[i], bv[j], acc[i][j], 0,0,0);
    __builtin_amdgcn_s_setprio(0);
  }
  float* Cf = (float*)Cv + (size_t)blockIdx.z * M * ldc;
  u16*   Cb = (u16*)Cv;
#pragma unroll
  for (int i = 0; i < 4; i++){
    int rbase = m0 + wr*64 + i*16 + ((lane>>4)<<2);
#pragma unroll
    for (int j = 0; j < 2; j++){
      int col = n0 + wc*32 + j*16 + (lane&15);
      if (col >= N) continue;
#pragma unroll
      for (int q = 0; q < 4; q++){
        int row = rbase + q;
        if (row >= M) continue;
        float v = acc[i][j][q];
        if (EPI == 1){ v += aux[col]; v = (v > 20.f) ? v : __logf(1.f + __expf(v)); }
        if (OB) Cb[(size_t)row*ldc + col] = bfr(v);
        else    Cf[(size_t)row*ldc + col] = v;
      }
    }
  }
}

// ------- grouped gate/up: counted-vmcnt dbuf, dual-B, silu fuse -----------
// grid: x = n-tile (16), y = compact tile index
__global__ __launch_bounds__(512) void gateup8(
    const u16* __restrict__ Aall,
    const u16* __restrict__ Wg, const u16* __restrict__ Wu,
    const int* __restrict__ cnt, const int* __restrict__ off,
    const int* __restrict__ bucket,
    const int* __restrict__ tmap, const int* __restrict__ ntot,
    u16* __restrict__ H)
{
  if ((int)blockIdx.y >= *ntot) return;
  int v = tmap[blockIdx.y];
  int e = v >> 16, m0 = (v & 0xFFFF) * 128;
  int Me = cnt[e];
  __shared__ u16 As[2*4096], Gs[2*4096], Us[2*4096];
  int tid = threadIdx.x, lane = tid & 63, wid = tid >> 6;
  int wr = wid >> 2, wc = wid & 3;
  int n0 = blockIdx.x * 128;
  int r = tid >> 2;
  int kk = ((tid & 3) ^ (r & 3)) * 8;
  int arow = bucket[e*Tn + min(m0 + r, Me-1)];
  const u16* Ag = Aall + (size_t)arow*Dm + kk;
  const u16* Gg = Wg + ((size_t)e*FFc + n0 + r)*Dm + kk;
  const u16* Ug = Wu + ((size_t)e*FFc + n0 + r)*Dm + kk;
  f32x4 ag[4][2] = {}, au[4][2] = {};
  int sw = ((lane>>4) ^ (lane&3)) * 8;
  int aoff[4], boff[2];
#pragma unroll
  for (int i = 0; i < 4; i++) aoff[i] = (wr*64 + i*16 + (lane&15))*32 + sw;
#pragma unroll
  for (int j = 0; j < 2; j++) boff[j] = (wc*32 + j*16 + (lane&15))*32 + sw;
  gload16(Ag, As + tid*8);
  gload16(Gg, Gs + tid*8);
  gload16(Ug, Us + tid*8);
  const int NT = Dm >> 5;
  for (int kt = 0; kt < NT; kt++){
    int cur = (kt & 1) * 4096;
    if (kt + 1 < NT){
      int nxt = 4096 - cur;
      gload16(Ag + (size_t)(kt+1)*32, As + nxt + tid*8);
      gload16(Gg + (size_t)(kt+1)*32, Gs + nxt + tid*8);
      gload16(Ug + (size_t)(kt+1)*32, Us + nxt + tid*8);
      asm volatile("s_waitcnt vmcnt(3)" ::: "memory");
    } else {
      asm volatile("s_waitcnt vmcnt(0)" ::: "memory");
    }
    __builtin_amdgcn_s_barrier();
    bf16x8 af[4], gf[2], uf[2];
#pragma unroll
    for (int i = 0; i < 4; i++) af[i] = *(const bf16x8*)&As[cur + aoff[i]];
#pragma unroll
    for (int j = 0; j < 2; j++){ gf[j] = *(const bf16x8*)&Gs[cur + boff[j]];
                                 uf[j] = *(const bf16x8*)&Us[cur + boff[j]]; }
    asm volatile("s_waitcnt lgkmcnt(0)" ::: "memory");
    __builtin_amdgcn_sched_barrier(0);
    __builtin_amdgcn_s_barrier();
    __builtin_amdgcn_s_setprio(1);
#pragma unroll
    for (int i = 0; i < 4; i++)
#pragma unroll
      for (int j = 0; j < 2; j++){
        ag[i][j] = __builtin_amdgcn_mfma_f32_16x16x32_bf16(af[i], gf[j], ag[i][j], 0,0,0);
        au[i][j] = __builtin_amdgcn_mfma_f32_16x16x32_bf16(af[i], uf[j], au[i][j], 0,0,0);
      }
    __builtin_amdgcn_s_setprio(0);
  }
  int offe = off[e];
#pragma unroll
  for (int i = 0; i < 4; i++){
    int mb = m0 + wr*64 + i*16 + ((lane>>4)<<2);
#pragma unroll
    for (int j = 0; j < 2; j++){
      int col = n0 + wc*32 + j*16 + (lane&15);
#pragma unroll
      for (int q = 0; q < 4; q++){
        int m = mb + q;
        if (m >= Me) continue;
        float g = ag[i][j][q], u = au[i][j][q];
        H[(size_t)(offe + m)*FFc + col] = bfr(siluf(g)*u);
      }
    }
  }
}

// ------------- grouped down: counted-vmcnt dbuf, K-split x2 ---------------
// grid: x = n-tile (8), y = compact tile index, z = K-half
__global__ __launch_bounds__(512) void down8(
    const u16* __restrict__ Hall, const u16* __restrict__ Wd,
    const int* __restrict__ cnt, const int* __restrict__ off,
    const int* __restrict__ tmap, const int* __restrict__ ntot,
    u16* __restrict__ Y)
{
  if ((int)blockIdx.y >= *ntot) return;
  int v = tmap[blockIdx.y];
  int e = v >> 16, m0 = (v & 0xFFFF) * 128;
  int Me = cnt[e];
  int offe = off[e];
  int kbeg = blockIdx.z * (FFc/2);
  const u16* A = Hall + (size_t)offe*FFc;
  const u16* B = Wd + (size_t)e*Dm*FFc;
  u16* C = Y + (size_t)blockIdx.z*(2*Tn)*Dm + (size_t)offe*Dm;
  __shared__ u16 As[2*4096], Bs[2*4096];
  int tid = threadIdx.x, lane = tid & 63, wid = tid >> 6;
  int wr = wid >> 2, wc = wid & 3;
  int n0 = blockIdx.x * 128;
  int r = tid >> 2;
  int kk = ((tid & 3) ^ (r & 3)) * 8;
  const u16* Ag = A + (size_t)min(m0 + r, Me-1)*FFc + kbeg + kk;
  const u16* Bg = B + (size_t)(n0 + r)*FFc + kbeg + kk;
  f32x4 acc[4][2] = {};
  int sw = ((lane>>4) ^ (lane&3)) * 8;
  int aoff[4], boff[2];
#pragma unroll
  for (int i = 0; i < 4; i++) aoff[i] = (wr*64 + i*16 + (lane&15))*32 + sw;
#pragma unroll
  for (int j = 0; j < 2; j++) boff[j] = (wc*32 + j*16 + (lane&15))*32 + sw;
  gload16(Ag, As + tid*8);
  gload16(Bg, Bs + tid*8);
  const int NT = (FFc/2) >> 5;
  for (int kt = 0; kt < NT; kt++){
    int cur = (kt & 1) * 4096;
    if (kt + 1 < NT){
      int nxt = 4096 - cur;
      gload16(Ag + (size_t)(kt+1)*32, As + nxt + tid*8);
      gload16(Bg + (size_t)(kt+1)*32, Bs + nxt + tid*8);
      asm volatile("s_waitcnt vmcnt(2)" ::: "memory");
    } else {
      asm volatile("s_waitcnt vmcnt(0)" ::: "memory");
    }
    __builtin_amdgcn_s_barrier();
    bf16x8 af[4], bv[2];
#pragma unroll
    for (int i = 0; i < 4; i++) af[i] = *(const bf16x8*)&As[cur + aoff[i]];
#pragma unroll
    for (int j = 0; j < 2; j++) bv[j] = *(const bf16x8*)&Bs[cur + boff[j]];
    asm volatile("s_waitcnt lgkmcnt(0)" ::: "memory");
    __builtin_amdgcn_sched_barrier(0);
    __builtin_amdgcn_s_barrier();
    __builtin_amdgcn_s_setprio(1);
#pragma unroll
    for (int i = 0; i < 4; i++)
#pragma unroll
      for (int j = 0; j < 2; j++)
        acc[i][j] = __builtin_amdgcn_mfma_f32_16x16x32_bf16(af[i], bv[j], acc[i][j], 0,0,0);
    __builtin_amdgcn_s_setprio(0);
  }
#pragma unroll
  for (int i = 0; i < 4; i++){
    int mb = m0 + wr*64 + i*16 + ((lane>>4)<<2);
#pragma unroll
    for (int j = 0; j < 2; j++){
      int col = n0 + wc*32 + j*16 + (lane&15);
#pragma unroll
      for (int q = 0; q < 4; q++){
        int m = mb + q;
        if (m >= Me) continue;
        C[(size_t)m*Dm + col] = bfr(acc[i][j][q]);
      }
    }
  }
}

// -------- depthwise causal conv (K=4) + bias + silu; bf16 in/out ----------
__global__ __launch_bounds__(256) void conv_k(const u16* __restrict__ xzb,
    const float* __restrict__ cw, const float* __restrict__ cb,
    u16* __restrict__ xc)
{
  int idx = blockIdx.x*256 + threadIdx.x;
  int t = idx >> 11, e = idx & (EDc - 1);
  float v = cb[e];
#pragma unroll
  for (int k = 0; k < 4; k++){
    int tt = t - 3 + k;
    if (tt >= 0) v += b2f(xzb[(size_t)tt*(2*EDc) + e]) * cw[e*4 + k];
  }
  xc[(size_t)t*EDc + e] = bfr(siluf(v));
}

// ---------- reduce 4 K-slices of xp, emit xp fp32 + dtA bf16 --------------
__global__ __launch_bounds__(256) void xp_red(const float* __restrict__ part,
                                              float* __restrict__ xp,
                                              u16* __restrict__ dtA){
  int i = blockIdx.x*256 + threadIdx.x;
  const int S = Tn*96;
  float v = part[i] + part[S + i] + part[2*S + i] + part[3*S + i];
  xp[i] = v;
  int t = i / 96, c = i - t*96;
  if (c < Rr) dtA[t*Rr + c] = bfr(v);
}

// ====================== SCAN: n-in-register version =======================
__global__ __launch_bounds__(256) void scan_p1(
  const u16* __restrict__ delta, const u16* __restrict__ xc,
  const float* __restrict__ xp,  const float* __restrict__ A_log,
  float* __restrict__ hend, float* __restrict__ dsum)
{
  __shared__ u16 sdel[SCH*256], sxc[SCH*256];
  __shared__ float sB[SCH*16];
  int tid = threadIdx.x;
  int e0 = blockIdx.x*256, c = blockIdx.y, t0 = c*SCH;
#pragma unroll
  for (int i = 0; i < 4; i++){
    int f = (i*256+tid)*8;
    int t = f >> 8, e = f & 255;
    gload16(&delta[(size_t)(t0+t)*EDc + e0 + e], sdel + f);
    gload16(&xc  [(size_t)(t0+t)*EDc + e0 + e], sxc + f);
  }
  sB[tid]       = xp[(size_t)(t0 + (tid>>4))*96 + Rr + (tid&15)];
  sB[tid+256]   = xp[(size_t)(t0 + ((tid+256)>>4))*96 + Rr + (tid&15)];
  float a2[16];
  {
    const float* ar = &A_log[(size_t)(e0+tid)*16];
#pragma unroll
    for (int n = 0; n < 16; n++) a2[n] = -__expf(ar[n]) * LOG2E;
  }
  __syncthreads();
  float h[16] = {};
  float ds = 0.f;
  for (int t = 0; t < SCH; t++){
    float del = b2f(sdel[t*256 + tid]);
    float xv  = b2f(sxc [t*256 + tid]);
    ds += del;
    float dbx = del * xv;
    float4 b0 = *(const float4*)&sB[t*16];
    float4 b1 = *(const float4*)&sB[t*16+4];
    float4 b2 = *(const float4*)&sB[t*16+8];
    float4 b3 = *(const float4*)&sB[t*16+12];
    float bb[16] = {b0.x,b0.y,b0.z,b0.w, b1.x,b1.y,b1.z,b1.w,
                    b2.x,b2.y,b2.z,b2.w, b3.x,b3.y,b3.z,b3.w};
#pragma unroll
    for (int n = 0; n < 16; n++){
      float dA = exp2f(del * a2[n]);
      h[n] = fmaf(dA, h[n], dbx * bb[n]);
    }
  }
  float* hp = &hend[((size_t)c*EDc + e0 + tid)*16];
#pragma unroll
  for (int n = 0; n < 16; n += 4)
    *(float4*)&hp[n] = make_float4(h[n], h[n+1], h[n+2], h[n+3]);
  dsum[c*EDc + e0 + tid] = ds;
}

__global__ __launch_bounds__(256) void scan_p2(
  const float* __restrict__ hend, const float* __restrict__ dsum,
  const float* __restrict__ A_log, float* __restrict__ hin)
{
  int g = blockIdx.x*256 + threadIdx.x;
  int e = g >> 4;
  float a2 = -__expf(A_log[g]) * LOG2E;
  float h = 0.f;
  for (int c = 0; c < SNCH; c++){
    hin[(size_t)c*EDc*Ns + g] = h;
    float P = exp2f(a2 * dsum[c*EDc + e]);
    h = fmaf(P, h, hend[(size_t)c*EDc*Ns + g]);
  }
}

__global__ __launch_bounds__(256) void scan_p3(
  const u16* __restrict__ delta, const u16* __restrict__ xc,
  const float* __restrict__ xp,  const u16* __restrict__ xzb,
  const float* __restrict__ A_log, const float* __restrict__ D_skip,
  const float* __restrict__ hin,   u16* __restrict__ y2)
{
  __shared__ u16 sdel[SCH*256], sxc[SCH*256], sz[SCH*256];
  __shared__ float sB[SCH*16], sC[SCH*16];
  int tid = threadIdx.x;
  int e0 = blockIdx.x*256, c = blockIdx.y, t0 = c*SCH;
#pragma unroll
  for (int i = 0; i < 4; i++){
    int f = (i*256+tid)*8;
    int t = f >> 8, e = f & 255;
    gload16(&delta[(size_t)(t0+t)*EDc + e0 + e], sdel + f);
    gload16(&xc  [(size_t)(t0+t)*EDc + e0 + e], sxc + f);
    gload16(&xzb [(size_t)(t0+t)*(2*EDc) + EDc + e0 + e], sz + f);
  }
  {
    int f0 = tid, f1 = tid + 256;
    sB[f0] = xp[(size_t)(t0 + (f0>>4))*96 + Rr + (f0&15)];
    sB[f1] = xp[(size_t)(t0 + (f1>>4))*96 + Rr + (f1&15)];
    sC[f0] = xp[(size_t)(t0 + (f0>>4))*96 + Rr + Ns + (f0&15)];
    sC[f1] = xp[(size_t)(t0 + (f1>>4))*96 + Rr + Ns + (f1&15)];
  }
  float a2[16];
  {
    const float* ar = &A_log[(size_t)(e0+tid)*16];
#pragma unroll
    for (int n = 0; n < 16; n++) a2[n] = -__expf(ar[n]) * LOG2E;
  }
  float dsk = D_skip[e0 + tid];
  float h[16];
  {
    const float* hp = &hin[((size_t)c*EDc + e0 + tid)*16];
#pragma unroll
    for (int n = 0; n < 16; n += 4){
      float4 hv = *(const float4*)&hp[n];
      h[n] = hv.x; h[n+1] = hv.y; h[n+2] = hv.z; h[n+3] = hv.w;
    }
  }
  __syncthreads();
  for (int t = 0; t < SCH; t++){
    float del = b2f(sdel[t*256 + tid]);
    float xv  = b2f(sxc [t*256 + tid]);
    float zv  = b2f(sz  [t*256 + tid]);
    float dbx = del * xv;
    float4 b0 = *(const float4*)&sB[t*16];
    float4 b1 = *(const float4*)&sB[t*16+4];
    float4 b2 = *(const float4*)&sB[t*16+8];
    float4 b3 = *(const float4*)&sB[t*16+12];
    float bb[16] = {b0.x,b0.y,b0.z,b0.w, b1.x,b1.y,b1.z,b1.w,
                    b2.x,b2.y,b2.z,b2.w, b3.x,b3.y,b3.z,b3.w};
    float4 c0 = *(const float4*)&sC[t*16];
    float4 c1 = *(const float4*)&sC[t*16+4];
    float4 c2 = *(const float4*)&sC[t*16+8];
    float4 c3 = *(const float4*)&sC[t*16+12];
    float cc[16] = {c0.x,c0.y,c0.z,c0.w, c1.x,c1.y,c1.z,c1.w,
                    c2.x,c2.y,c2.z,c2.w, c3.x,c3.y,c3.z,c3.w};
    float p0 = 0.f, p1 = 0.f, p2 = 0.f, p3 = 0.f;
#pragma unroll
    for (int n = 0; n < 16; n += 4){
      float dA0 = exp2f(del * a2[n]);
      float dA1 = exp2f(del * a2[n+1]);
      float dA2 = exp2f(del * a2[n+2]);
      float dA3 = exp2f(del * a2[n+3]);
      h[n]   = fmaf(dA0, h[n],   dbx * bb[n]);
      h[n+1] = fmaf(dA1, h[n+1], dbx * bb[n+1]);
      h[n+2] = fmaf(dA2, h[n+2], dbx * bb[n+2]);
      h[n+3] = fmaf(dA3, h[n+3], dbx * bb[n+3]);
      p0 = fmaf(h[n],   cc[n],   p0);
      p1 = fmaf(h[n+1], cc[n+1], p1);
      p2 = fmaf(h[n+2], cc[n+2], p2);
      p3 = fmaf(h[n+3], cc[n+3], p3);
    }
    float p = (p0 + p1) + (p2 + p3);
    y2[(size_t)(t0+t)*EDc + e0 + tid] = bfr((p + dsk*xv) * siluf(zv));
  }
}

// ------------- router ------------------------------------------------------
__global__ __launch_bounds__(256) void route_k(
  const float* __restrict__ h2, const float* __restrict__ Wr,
  float* __restrict__ logits_out,
  int* __restrict__ cnt, int* __restrict__ bucket,
  int* __restrict__ tok_e, int* __restrict__ tok_idx, float* __restrict__ tok_w)
{
  int t = blockIdx.x, tid = threadIdx.x;
  float p[8] = {};
#pragma unroll
  for (int j = 0; j < 4; j++){
    int d = tid + j*256;
    float xv = h2[(size_t)t*Dm + d];
#pragma unroll
    for (int e = 0; e < 8; e++) p[e] += xv * Wr[e*Dm + d];
  }
#pragma unroll
  for (int e = 0; e < 8; e++)
#pragma unroll
    for (int m = 1; m < 64; m <<= 1) p[e] += __shfl_xor(p[e], m);
  __shared__ float part[4][8];
  __shared__ float lg[8];
  int lane = tid & 63, wv = tid >> 6;
  if (lane == 0)
#pragma unroll
    for (int e = 0; e < 8; e++) part[wv][e] = p[e];
  __syncthreads();
  if (tid < 8){
    float v = part[0][tid]+part[1][tid]+part[2][tid]+part[3][tid];
    lg[tid] = v;
    logits_out[(size_t)t*8 + tid] = v;
  }
  __syncthreads();
  if (tid == 0){
    float mx = lg[0];
#pragma unroll
    for (int e = 1; e < 8; e++) mx = fmaxf(mx, lg[e]);
    float ex[8], s = 0.f;
#pragma unroll
    for (int e = 0; e < 8; e++){ ex[e] = expf(lg[e] - mx); s += ex[e]; }
    float inv = 1.f / s;
    int i0 = 0; float b0 = ex[0]*inv;
#pragma unroll
    for (int e = 1; e < 8; e++){ float pe = ex[e]*inv; if (pe > b0){ b0 = pe; i0 = e; } }
    int i1 = -1; float b1 = -1e30f;
#pragma unroll
    for (int e = 0; e < 8; e++){ if (e == i0) continue; float pe = ex[e]*inv; if (pe > b1){ b1 = pe; i1 = e; } }
    int k0 = atomicAdd(&cnt[i0], 1); bucket[i0*Tn + k0] = t;
    int k1 = atomicAdd(&cnt[i1], 1); bucket[i1*Tn + k1] = t;
    tok_e[2*t] = i0;   tok_idx[2*t] = k0;   tok_w[2*t] = b0;
    tok_e[2*t+1] = i1; tok_idx[2*t+1] = k1; tok_w[2*t+1] = b1;
  }
}

// ---------- offsets + compact (expert, m-tile) map ------------------------
__global__ void prefix_k(const int* __restrict__ cnt, int* __restrict__ off,
                         int* __restrict__ tmap, int* __restrict__ ntot){
  if (threadIdx.x == 0 && blockIdx.x == 0){
    int s = 0;
    for (int e = 0; e < NEx; e++){ off[e] = s; s += cnt[e]; }
    int nt = 0;
    for (int e = 0; e < NEx; e++){
      int tiles = (cnt[e] + 127) >> 7;
      for (int tm = 0; tm < tiles; tm++) tmap[nt++] = (e << 16) | tm;
    }
    *ntot = nt;
  }
}

// ---------------- final combine (2 bf16 K-split slabs) --------------------
__global__ __launch_bounds__(256) void combine_k(float* __restrict__ out,
    const u16* __restrict__ Y, const int* __restrict__ off,
    const int* __restrict__ tok_e, const int* __restrict__ tok_idx,
    const float* __restrict__ tok_w)
{
  int t = blockIdx.x, tid = threadIdx.x;
  const size_t S2 = (size_t)(2*Tn)*Dm;
  int e0 = tok_e[2*t],   e1 = tok_e[2*t+1];
  size_t r0 = (size_t)(off[e0] + tok_idx[2*t])*Dm;
  size_t r1 = (size_t)(off[e1] + tok_idx[2*t+1])*Dm;
  float w0 = tok_w[2*t], w1 = tok_w[2*t+1];
#pragma unroll
  for (int j = 0; j < 4; j++){
    int d = tid + j*256;
    float y0 = b2f(Y[r0 + d]) + b2f(Y[S2 + r0 + d]);
    float y1 = b2f(Y[r1 + d]) + b2f(Y[S2 + r1 + d]);
    out[(size_t)t*Dm + d] += w0*y0 + w1*y1;
  }
}

extern "C" void kernel_launch(void* const* d_in, const int* in_sizes, int n_in,
                              void* d_out, int out_size, void* d_ws, size_t ws_size,
                              hipStream_t stream) {
  const float* x      = (const float*)d_in[0];
  const float* rms1_w = (const float*)d_in[1];
  const float* rms2_w = (const float*)d_in[2];
  const float* W_in   = (const float*)d_in[3];
  const float* conv_w = (const float*)d_in[4];
  const float* conv_b = (const float*)d_in[5];
  const float* W_xprj = (const float*)d_in[6];
  const float* W_dt   = (const float*)d_in[7];
  const float* b_dt   = (const float*)d_in[8];
  const float* A_log  = (const float*)d_in[9];
  const float* D_skip = (const float*)d_in[10];
  const float* W_out  = (const float*)d_in[11];
  const float* W_rt   = (const float*)d_in[12];
  const float* gate_w = (const float*)d_in[13];
  const float* up_w   = (const float*)d_in[14];
  const float* down_w = (const float*)d_in[15];

  float* out        = (float*)d_out;
  float* logits_out = out + (size_t)Tn*Dm;

  uint8_t* base = (uint8_t*)d_ws;
  size_t o = 0;
  auto alloc = [&](size_t bytes) -> void* {
    void* p = base + o;
    o = (o + bytes + 255) & ~(size_t)255;
    return p;
  };
  // ---- survivors (live through MoE phase) ----
  float* h2f   = (float*)alloc((size_t)Tn*Dm*4);
  u16*   h2b   = (u16*)  alloc((size_t)Tn*Dm*2);
  u16*   hmoe  = (u16*)  alloc((size_t)2*Tn*FFc*2);
  u16*   yslot = (u16*)  alloc((size_t)2*(2*Tn)*Dm*2);
  int*   cnt     = (int*)alloc(64);
  int*   off     = (int*)alloc(64);
  int*   ntot    = (int*)alloc(64);
  int*   tmap    = (int*)alloc(MAXTM*4 + 192);
  int*   bucket  = (int*)alloc((size_t)NEx*Tn*4);
  int*   tok_e   = (int*)alloc((size_t)2*Tn*4);
  int*   tok_idx = (int*)alloc((size_t)2*Tn*4);
  float* tok_w   = (float*)alloc((size_t)2*Tn*4);
  // ---- overlap zone: mamba-phase buffers also host bf16 MoE weights ----
  size_t oz = o;
  u16*   xzb   = (u16*)  alloc((size_t)Tn*2*EDc*2);
  u16*   delta = (u16*)  alloc((size_t)Tn*EDc*2);
  u16*   xc    = (u16*)  alloc((size_t)Tn*EDc*2);
  u16*   y2    = (u16*)  alloc((size_t)Tn*EDc*2);
  u16*   h1b   = (u16*)  alloc((size_t)Tn*Dm*2);
  u16*   dtA   = (u16*)  alloc((size_t)Tn*Rr*2);
  float* xp    = (float*)alloc((size_t)Tn*96*4);
  float* xp_part=(float*)alloc((size_t)4*Tn*96*4);
  float* hend  = (float*)alloc((size_t)SNCH*EDc*Ns*4);
  float* hin   = (float*)alloc((size_t)SNCH*EDc*Ns*4);
  float* dsum  = (float*)alloc((size_t)SNCH*EDc*4);
  // W_out K-split partials alias over xzb+delta+xc (dead by then)
  float* wpart = (float*)xzb;
  // MoE bf16 weights overlay the dead mamba buffers
  u16* wgate = (u16*)(base + oz);
  u16* wup   = wgate + (size_t)NEx*FFc*Dm;
  u16* wdown = wup   + (size_t)NEx*FFc*Dm;
  // mamba bf16 weights overlay the dead-until-MoE survivors
  u16* wbin  = (u16*)yslot;
  u16* wbout = wbin + (size_t)2*EDc*Dm;
  u16* wxp   = (u16*)hmoe;
  u16* wdt   = wxp + (size_t)96*EDc;

  // 0) convert all four mamba weights to bf16 in ONE launch
  {
    int n0 = 2*EDc*Dm/4, n1 = Dm*EDc/4, n2 = 96*EDc/4, n3 = EDc*Rr/4;
    int tot = n0 + n1 + n2 + n3;
    f2bm_k<<<(tot + 255)/256, 256, 0, stream>>>(W_in, wbin, n0, W_out, wbout, n1,
                                                W_xprj, wxp, n2, W_dt, wdt, n3);
  }
  // 1) rmsnorm 1 -> h1b
  rmsnorm_k<<<Tn, 256, 0, stream>>>(x, rms1_w, h1b);
  // 2) xz = h1 @ W_in^T -> bf16  (grid x=n-tiles, y=m-tiles)
  gemm_bb<0,1><<<dim3(32,16,1), 512, 0, stream>>>(h1b, Dm, wbin, Dm, xzb, 2*EDc, Tn, 2*EDc, Dm, nullptr);
  // 3) conv + silu -> xc
  conv_k<<<(Tn*EDc)/256, 256, 0, stream>>>(xzb, conv_w, conv_b, xc);
  // 4) xp = xc @ W_xproj^T, K-split x4, then reduce (+ dtA)
  gemm_bb<0,0><<<dim3(1,16,4), 512, 0, stream>>>(xc, EDc, wxp, EDc, xp_part, 96, Tn, 96, EDc/4, nullptr);
  xp_red<<<(Tn*96)/256, 256, 0, stream>>>(xp_part, xp, dtA);
  // 5) delta = softplus(dtA @ W_dt^T + b_dt) -> bf16
  gemm_bb<1,1><<<dim3(16,16,1), 512, 0, stream>>>(dtA, Rr, wdt, Rr, delta, EDc, Tn, EDc, Rr, b_dt);
  // 6) chunked parallel scan -> y2
  scan_p1<<<dim3(EDc/256, SNCH), 256, 0, stream>>>(delta, xc, xp, A_log, hend, dsum);
  scan_p2<<<EDc*Ns/256, 256, 0, stream>>>(hend, dsum, A_log, hin);
  scan_p3<<<dim3(EDc/256, SNCH), 256, 0, stream>>>(delta, xc, xp, xzb, A_log, D_skip, hin, y2);
  // 7) y2 @ W_out^T, K-split x4 -> fp32 partials
  gemm_bb<0,0><<<dim3(8,16,4), 512, 0, stream>>>(y2, EDc, wbout, EDc, wpart, Dm, Tn, Dm, EDc/4, nullptr);
  // 8) fused: out = x + sum(partials); rmsnorm -> h2b + h2f
  rms2red_k<<<Tn, 256, 0, stream>>>(x, wpart, rms2_w, out, h2f, h2b);
  // 9) MoE weights -> bf16 (overlay zone), merged single launch
  f2b3_k<<<3*((NEx*FFc*Dm/4)/256), 256, 0, stream>>>(gate_w, up_w, down_w, wgate, wup, wdown);
  // 10) routing
  hipMemsetAsync(cnt, 0, 32, stream);
  route_k<<<Tn, 256, 0, stream>>>(h2f, W_rt, logits_out, cnt, bucket, tok_e, tok_idx, tok_w);
  prefix_k<<<1, 64, 0, stream>>>(cnt, off, tmap, ntot);
  // 11) expert gate/up (grid x=n-tiles, y=compact tiles)
  gateup8<<<dim3(16, MAXTM), 512, 0, stream>>>(h2b, wgate, wup, cnt, off, bucket, tmap, ntot, hmoe);
  // 12) expert down (grid x=n-tiles, y=compact tiles, z=K-half)
  down8<<<dim3(8, MAXTM, 2), 512, 0, stream>>>(hmoe, wdown, cnt, off, tmap, ntot, yslot);
  // 13) combine
  combine_k<<<Tn, 256, 0, stream>>>(out, yslot, off, tok_e, tok_idx, tok_w);
}

// Round 11
// 377.278 us; speedup vs baseline: 1.2846x; 1.0187x over previous
//
#include <hip/hip_runtime.h>
#include <math.h>

typedef unsigned short u16;
typedef unsigned int   u32;
typedef __attribute__((ext_vector_type(8))) short bf16x8;
typedef __attribute__((ext_vector_type(4))) float f32x4;

constexpr int Tn=2048, Dm=1024, EDc=2048, Ns=16, Rr=64, NEx=8, FFc=2048;
constexpr int SCH=32, SNCH=Tn/SCH;
constexpr int MAXTM=40;
constexpr float LOG2E = 1.44269504f;

__device__ __forceinline__ float siluf(float x){ return __fdividef(x, 1.f + __expf(-x)); }
__device__ __forceinline__ u16 bfr(float f){
  u32 u = __float_as_uint(f);
  return (u16)((u + 0x7fffu + ((u>>16)&1u)) >> 16);
}
__device__ __forceinline__ float b2f(u16 h){ return __uint_as_float(((u32)h)<<16); }

__device__ __forceinline__ void gload16(const void* g, void* l){
  __builtin_amdgcn_global_load_lds((const __attribute__((address_space(1))) void*)g,
                                   (__attribute__((address_space(3))) void*)l, 16, 0, 0);
}

__device__ __forceinline__ void cvt4(const float* __restrict__ in,
                                     u16* __restrict__ out, int i){
  float4 v = ((const float4*)in)[i];
  u32 lo = (u32)bfr(v.x) | ((u32)bfr(v.y)<<16);
  u32 hi = (u32)bfr(v.z) | ((u32)bfr(v.w)<<16);
  ((uint2*)out)[i] = make_uint2(lo, hi);
}

// ---- merged 4-way mamba weight convert, 4x float4 per thread -------------
// block ranges (1024 float4 per block): W_in 1024, W_out 512, W_xproj 48, W_dt 32
__global__ __launch_bounds__(256) void f2bm_k(
    const float* __restrict__ i0, u16* __restrict__ o0,
    const float* __restrict__ i1, u16* __restrict__ o1,
    const float* __restrict__ i2, u16* __restrict__ o2,
    const float* __restrict__ i3, u16* __restrict__ o3)
{
  int b = blockIdx.x;
  const float* in; u16* out;
  if (b < 1024){ in = i0; out = o0; }
  else if ((b -= 1024) < 512){ in = i1; out = o1; }
  else if ((b -= 512) < 48){ in = i2; out = o2; }
  else { b -= 48; in = i3; out = o3; }
  int base = b*1024 + threadIdx.x;
#pragma unroll
  for (int s = 0; s < 4; s++) cvt4(in, out, base + s*256);
}

// ---- merged 3-way MoE weight convert, 4x float4 per thread ---------------
__global__ __launch_bounds__(256) void f2b3_k(
    const float* __restrict__ g, const float* __restrict__ u,
    const float* __restrict__ d,
    u16* __restrict__ og, u16* __restrict__ ou, u16* __restrict__ od){
  const int BPW = (NEx*FFc*Dm/4)/1024;   // 4096 blocks per tensor
  int b = blockIdx.x;
  int which = b / BPW;
  const float* in = (which==0) ? g : (which==1) ? u : d;
  u16* out        = (which==0) ? og : (which==1) ? ou : od;
  int base = (b - which*BPW)*1024 + threadIdx.x;
#pragma unroll
  for (int s = 0; s < 4; s++) cvt4(in, out, base + s*256);
}

// ---------------- rmsnorm (bf16 out only) ---------------------------------
__global__ __launch_bounds__(256) void rmsnorm_k(const float* __restrict__ x,
                                                 const float* __restrict__ w,
                                                 u16* __restrict__ ob){
  int t = blockIdx.x;
  const float* xr = x + (size_t)t * Dm;
  float v[4]; float s = 0.f;
#pragma unroll
  for (int j = 0; j < 4; j++){ int d = threadIdx.x + j*256; v[j] = xr[d]; s += v[j]*v[j]; }
#pragma unroll
  for (int m = 1; m < 64; m <<= 1) s += __shfl_xor(s, m);
  __shared__ float red[4]; __shared__ float sb;
  int lane = threadIdx.x & 63, wv = threadIdx.x >> 6;
  if (lane == 0) red[wv] = s;
  __syncthreads();
  if (threadIdx.x == 0) sb = rsqrtf((red[0]+red[1]+red[2]+red[3]) * (1.f/Dm) + 1e-6f);
  __syncthreads();
  float sc = sb;
#pragma unroll
  for (int j = 0; j < 4; j++){
    int d = threadIdx.x + j*256;
    ob[(size_t)t*Dm + d] = bfr(v[j]*sc*w[d]);
  }
}

// ---- fused: out = x + sum4(P); rmsnorm(out) -> h2b bf16 + h2f fp32 -------
// also zeroes the router's expert counters (saves a memset launch)
__global__ __launch_bounds__(256) void rms2red_k(
  const float* __restrict__ x, const float* __restrict__ P,
  const float* __restrict__ w,
  float* __restrict__ out, float* __restrict__ h2f, u16* __restrict__ h2b,
  int* __restrict__ cnt)
{
  int t = blockIdx.x, tid = threadIdx.x;
  if (t == 0 && tid < 8) cnt[tid] = 0;
  const size_t S = (size_t)Tn*Dm;
  float v[4]; float s = 0.f;
#pragma unroll
  for (int j = 0; j < 4; j++){
    int d = tid + j*256;
    size_t idx = (size_t)t*Dm + d;
    float a = x[idx] + ((P[idx] + P[S+idx]) + (P[2*S+idx] + P[3*S+idx]));
    out[idx] = a; v[j] = a; s += a*a;
  }
#pragma unroll
  for (int m = 1; m < 64; m <<= 1) s += __shfl_xor(s, m);
  __shared__ float red[4]; __shared__ float sb;
  int lane = tid & 63, wv = tid >> 6;
  if (lane == 0) red[wv] = s;
  __syncthreads();
  if (tid == 0) sb = rsqrtf((red[0]+red[1]+red[2]+red[3]) * (1.f/Dm) + 1e-6f);
  __syncthreads();
  float sc = sb;
#pragma unroll
  for (int j = 0; j < 4; j++){
    int d = tid + j*256;
    float o = v[j]*sc*w[d];
    h2b[(size_t)t*Dm + d] = bfr(o);
    h2f[(size_t)t*Dm + d] = o;
  }
}

// ---- all-bf16 MFMA GEMM, 512 thr, 128x128 tile, counted-vmcnt dbuf -------
// grid: x = n-tile, y = m-tile, z = K-slice
template<int EPI, int OB>
__global__ __launch_bounds__(512) void gemm_bb(
    const u16* __restrict__ A, int lda,
    const u16* __restrict__ B, int ldb,
    void* __restrict__ Cv, int ldc,
    int M, int N, int Ksl, const float* __restrict__ aux)
{
  __shared__ u16 As[2*4096], Bs[2*4096];
  int tid = threadIdx.x, lane = tid & 63, wid = tid >> 6;
  int wr = wid >> 2, wc = wid & 3;
  int n0 = blockIdx.x * 128, m0 = blockIdx.y * 128;
  int r = tid >> 2;
  int kk = ((tid & 3) ^ (r & 3)) * 8;                 // swizzled slot (write side)
  size_t kbeg = (size_t)blockIdx.z * Ksl;
  const u16* Ag = A + (size_t)min(m0 + r, M-1)*lda + kbeg + kk;
  const u16* Bg = B + (size_t)min(n0 + r, N-1)*ldb + kbeg + kk;
  f32x4 acc[4][2] = {};
  int sw = ((lane>>4) ^ (lane&3)) * 8;                // swizzled slot (read side)
  int aoff[4], boff[2];
#pragma unroll
  for (int i = 0; i < 4; i++) aoff[i] = (wr*64 + i*16 + (lane&15))*32 + sw;
#pragma unroll
  for (int j = 0; j < 2; j++) boff[j] = (wc*32 + j*16 + (lane&15))*32 + sw;
  gload16(Ag, As + tid*8);
  gload16(Bg, Bs + tid*8);
  int NT = Ksl >> 5;
  for (int kt = 0; kt < NT; kt++){
    int cur = (kt & 1) * 4096;
    if (kt + 1 < NT){
      int nxt = 4096 - cur;
      gload16(Ag + (size_t)(kt+1)*32, As + nxt + tid*8);
      gload16(Bg + (size_t)(kt+1)*32, Bs + nxt + tid*8);
      asm volatile("s_waitcnt vmcnt(2)" ::: "memory");
    } else {
      asm volatile("s_waitcnt vmcnt(0)" ::: "memory");
    }
    __builtin_amdgcn_s_barrier();
    bf16x8 af[4], bv[2];
#pragma unroll
    for (int i = 0; i < 4; i++) af[i] = *(const bf16x8*)&As[cur + aoff[i]];
#pragma unroll
    for (int j = 0; j < 2; j++) bv[j] = *(const bf16x8*)&Bs[cur + boff[j]];
    asm volatile("s_waitcnt lgkmcnt(0)" ::: "memory");
    __builtin_amdgcn_sched_barrier(0);
    __builtin_amdgcn_s_barrier();
    __builtin_amdgcn_s_setprio(1);
#pragma unroll
    for (int i = 0; i < 4; i++)
#pragma unroll
      for (int j = 0; j < 2; j++)
        acc[i][j] = __builtin_amdgcn_mfma_f32_16x16x32_bf16(af[i], bv[j], acc[i][j], 0,0,0);
    __builtin_amdgcn_s_setprio(0);
  }
  float* Cf = (float*)Cv + (size_t)blockIdx.z * M * ldc;
  u16*   Cb = (u16*)Cv;
#pragma unroll
  for (int i = 0; i < 4; i++){
    int rbase = m0 + wr*64 + i*16 + ((lane>>4)<<2);
#pragma unroll
    for (int j = 0; j < 2; j++){
      int col = n0 + wc*32 + j*16 + (lane&15);
      if (col >= N) continue;
#pragma unroll
      for (int q = 0; q < 4; q++){
        int row = rbase + q;
        if (row >= M) continue;
        float v = acc[i][j][q];
        if (EPI == 1){ v += aux[col]; v = (v > 20.f) ? v : __logf(1.f + __expf(v)); }
        if (OB) Cb[(size_t)row*ldc + col] = bfr(v);
        else    Cf[(size_t)row*ldc + col] = v;
      }
    }
  }
}

// ------- grouped gate/up: counted-vmcnt dbuf, dual-B, silu fuse -----------
// grid: x = n-tile (16), y = compact tile index
__global__ __launch_bounds__(512) void gateup8(
    const u16* __restrict__ Aall,
    const u16* __restrict__ Wg, const u16* __restrict__ Wu,
    const int* __restrict__ cnt, const int* __restrict__ off,
    const int* __restrict__ bucket,
    const int* __restrict__ tmap, const int* __restrict__ ntot,
    u16* __restrict__ H)
{
  if ((int)blockIdx.y >= *ntot) return;
  int v = tmap[blockIdx.y];
  int e = v >> 16, m0 = (v & 0xFFFF) * 128;
  int Me = cnt[e];
  __shared__ u16 As[2*4096], Gs[2*4096], Us[2*4096];
  int tid = threadIdx.x, lane = tid & 63, wid = tid >> 6;
  int wr = wid >> 2, wc = wid & 3;
  int n0 = blockIdx.x * 128;
  int r = tid >> 2;
  int kk = ((tid & 3) ^ (r & 3)) * 8;
  int arow = bucket[e*Tn + min(m0 + r, Me-1)];
  const u16* Ag = Aall + (size_t)arow*Dm + kk;
  const u16* Gg = Wg + ((size_t)e*FFc + n0 + r)*Dm + kk;
  const u16* Ug = Wu + ((size_t)e*FFc + n0 + r)*Dm + kk;
  f32x4 ag[4][2] = {}, au[4][2] = {};
  int sw = ((lane>>4) ^ (lane&3)) * 8;
  int aoff[4], boff[2];
#pragma unroll
  for (int i = 0; i < 4; i++) aoff[i] = (wr*64 + i*16 + (lane&15))*32 + sw;
#pragma unroll
  for (int j = 0; j < 2; j++) boff[j] = (wc*32 + j*16 + (lane&15))*32 + sw;
  gload16(Ag, As + tid*8);
  gload16(Gg, Gs + tid*8);
  gload16(Ug, Us + tid*8);
  const int NT = Dm >> 5;
  for (int kt = 0; kt < NT; kt++){
    int cur = (kt & 1) * 4096;
    if (kt + 1 < NT){
      int nxt = 4096 - cur;
      gload16(Ag + (size_t)(kt+1)*32, As + nxt + tid*8);
      gload16(Gg + (size_t)(kt+1)*32, Gs + nxt + tid*8);
      gload16(Ug + (size_t)(kt+1)*32, Us + nxt + tid*8);
      asm volatile("s_waitcnt vmcnt(3)" ::: "memory");
    } else {
      asm volatile("s_waitcnt vmcnt(0)" ::: "memory");
    }
    __builtin_amdgcn_s_barrier();
    bf16x8 af[4], gf[2], uf[2];
#pragma unroll
    for (int i = 0; i < 4; i++) af[i] = *(const bf16x8*)&As[cur + aoff[i]];
#pragma unroll
    for (int j = 0; j < 2; j++){ gf[j] = *(const bf16x8*)&Gs[cur + boff[j]];
                                 uf[j] = *(const bf16x8*)&Us[cur + boff[j]]; }
    asm volatile("s_waitcnt lgkmcnt(0)" ::: "memory");
    __builtin_amdgcn_sched_barrier(0);
    __builtin_amdgcn_s_barrier();
    __builtin_amdgcn_s_setprio(1);
#pragma unroll
    for (int i = 0; i < 4; i++)
#pragma unroll
      for (int j = 0; j < 2; j++){
        ag[i][j] = __builtin_amdgcn_mfma_f32_16x16x32_bf16(af[i], gf[j], ag[i][j], 0,0,0);
        au[i][j] = __builtin_amdgcn_mfma_f32_16x16x32_bf16(af[i], uf[j], au[i][j], 0,0,0);
      }
    __builtin_amdgcn_s_setprio(0);
  }
  int offe = off[e];
#pragma unroll
  for (int i = 0; i < 4; i++){
    int mb = m0 + wr*64 + i*16 + ((lane>>4)<<2);
#pragma unroll
    for (int j = 0; j < 2; j++){
      int col = n0 + wc*32 + j*16 + (lane&15);
#pragma unroll
      for (int q = 0; q < 4; q++){
        int m = mb + q;
        if (m >= Me) continue;
        float g = ag[i][j][q], u = au[i][j][q];
        H[(size_t)(offe + m)*FFc + col] = bfr(siluf(g)*u);
      }
    }
  }
}

// ------------- grouped down: counted-vmcnt dbuf, K-split x2 ---------------
// grid: x = n-tile (8), y = compact tile index, z = K-half
__global__ __launch_bounds__(512) void down8(
    const u16* __restrict__ Hall, const u16* __restrict__ Wd,
    const int* __restrict__ cnt, const int* __restrict__ off,
    const int* __restrict__ tmap, const int* __restrict__ ntot,
    u16* __restrict__ Y)
{
  if ((int)blockIdx.y >= *ntot) return;
  int v = tmap[blockIdx.y];
  int e = v >> 16, m0 = (v & 0xFFFF) * 128;
  int Me = cnt[e];
  int offe = off[e];
  int kbeg = blockIdx.z * (FFc/2);
  const u16* A = Hall + (size_t)offe*FFc;
  const u16* B = Wd + (size_t)e*Dm*FFc;
  u16* C = Y + (size_t)blockIdx.z*(2*Tn)*Dm + (size_t)offe*Dm;
  __shared__ u16 As[2*4096], Bs[2*4096];
  int tid = threadIdx.x, lane = tid & 63, wid = tid >> 6;
  int wr = wid >> 2, wc = wid & 3;
  int n0 = blockIdx.x * 128;
  int r = tid >> 2;
  int kk = ((tid & 3) ^ (r & 3)) * 8;
  const u16* Ag = A + (size_t)min(m0 + r, Me-1)*FFc + kbeg + kk;
  const u16* Bg = B + (size_t)(n0 + r)*FFc + kbeg + kk;
  f32x4 acc[4][2] = {};
  int sw = ((lane>>4) ^ (lane&3)) * 8;
  int aoff[4], boff[2];
#pragma unroll
  for (int i = 0; i < 4; i++) aoff[i] = (wr*64 + i*16 + (lane&15))*32 + sw;
#pragma unroll
  for (int j = 0; j < 2; j++) boff[j] = (wc*32 + j*16 + (lane&15))*32 + sw;
  gload16(Ag, As + tid*8);
  gload16(Bg, Bs + tid*8);
  const int NT = (FFc/2) >> 5;
  for (int kt = 0; kt < NT; kt++){
    int cur = (kt & 1) * 4096;
    if (kt + 1 < NT){
      int nxt = 4096 - cur;
      gload16(Ag + (size_t)(kt+1)*32, As + nxt + tid*8);
      gload16(Bg + (size_t)(kt+1)*32, Bs + nxt + tid*8);
      asm volatile("s_waitcnt vmcnt(2)" ::: "memory");
    } else {
      asm volatile("s_waitcnt vmcnt(0)" ::: "memory");
    }
    __builtin_amdgcn_s_barrier();
    bf16x8 af[4], bv[2];
#pragma unroll
    for (int i = 0; i < 4; i++) af[i] = *(const bf16x8*)&As[cur + aoff[i]];
#pragma unroll
    for (int j = 0; j < 2; j++) bv[j] = *(const bf16x8*)&Bs[cur + boff[j]];
    asm volatile("s_waitcnt lgkmcnt(0)" ::: "memory");
    __builtin_amdgcn_sched_barrier(0);
    __builtin_amdgcn_s_barrier();
    __builtin_amdgcn_s_setprio(1);
#pragma unroll
    for (int i = 0; i < 4; i++)
#pragma unroll
      for (int j = 0; j < 2; j++)
        acc[i][j] = __builtin_amdgcn_mfma_f32_16x16x32_bf16(af[i], bv[j], acc[i][j], 0,0,0);
    __builtin_amdgcn_s_setprio(0);
  }
#pragma unroll
  for (int i = 0; i < 4; i++){
    int mb = m0 + wr*64 + i*16 + ((lane>>4)<<2);
#pragma unroll
    for (int j = 0; j < 2; j++){
      int col = n0 + wc*32 + j*16 + (lane&15);
#pragma unroll
      for (int q = 0; q < 4; q++){
        int m = mb + q;
        if (m >= Me) continue;
        C[(size_t)m*Dm + col] = bfr(acc[i][j][q]);
      }
    }
  }
}

// -------- depthwise causal conv (K=4) + bias + silu; bf16 in/out ----------
__global__ __launch_bounds__(256) void conv_k(const u16* __restrict__ xzb,
    const float* __restrict__ cw, const float* __restrict__ cb,
    u16* __restrict__ xc)
{
  int idx = blockIdx.x*256 + threadIdx.x;
  int t = idx >> 11, e = idx & (EDc - 1);
  float v = cb[e];
#pragma unroll
  for (int k = 0; k < 4; k++){
    int tt = t - 3 + k;
    if (tt >= 0) v += b2f(xzb[(size_t)tt*(2*EDc) + e]) * cw[e*4 + k];
  }
  xc[(size_t)t*EDc + e] = bfr(siluf(v));
}

// ---------- reduce 4 K-slices of xp, emit xp fp32 + dtA bf16 --------------
__global__ __launch_bounds__(256) void xp_red(const float* __restrict__ part,
                                              float* __restrict__ xp,
                                              u16* __restrict__ dtA){
  int i = blockIdx.x*256 + threadIdx.x;
  const int S = Tn*96;
  float v = part[i] + part[S + i] + part[2*S + i] + part[3*S + i];
  xp[i] = v;
  int t = i / 96, c = i - t*96;
  if (c < Rr) dtA[t*Rr + c] = bfr(v);
}

// ====================== SCAN: n-in-register version =======================
__global__ __launch_bounds__(256) void scan_p1(
  const u16* __restrict__ delta, const u16* __restrict__ xc,
  const float* __restrict__ xp,  const float* __restrict__ A_log,
  float* __restrict__ hend, float* __restrict__ dsum)
{
  __shared__ u16 sdel[SCH*256], sxc[SCH*256];
  __shared__ float sB[SCH*16];
  int tid = threadIdx.x;
  int e0 = blockIdx.x*256, c = blockIdx.y, t0 = c*SCH;
#pragma unroll
  for (int i = 0; i < 4; i++){
    int f = (i*256+tid)*8;
    int t = f >> 8, e = f & 255;
    gload16(&delta[(size_t)(t0+t)*EDc + e0 + e], sdel + f);
    gload16(&xc  [(size_t)(t0+t)*EDc + e0 + e], sxc + f);
  }
  sB[tid]       = xp[(size_t)(t0 + (tid>>4))*96 + Rr + (tid&15)];
  sB[tid+256]   = xp[(size_t)(t0 + ((tid+256)>>4))*96 + Rr + (tid&15)];
  float a2[16];
  {
    const float* ar = &A_log[(size_t)(e0+tid)*16];
#pragma unroll
    for (int n = 0; n < 16; n++) a2[n] = -__expf(ar[n]) * LOG2E;
  }
  __syncthreads();
  float h[16] = {};
  float ds = 0.f;
  for (int t = 0; t < SCH; t++){
    float del = b2f(sdel[t*256 + tid]);
    float xv  = b2f(sxc [t*256 + tid]);
    ds += del;
    float dbx = del * xv;
    float4 b0 = *(const float4*)&sB[t*16];
    float4 b1 = *(const float4*)&sB[t*16+4];
    float4 b2 = *(const float4*)&sB[t*16+8];
    float4 b3 = *(const float4*)&sB[t*16+12];
    float bb[16] = {b0.x,b0.y,b0.z,b0.w, b1.x,b1.y,b1.z,b1.w,
                    b2.x,b2.y,b2.z,b2.w, b3.x,b3.y,b3.z,b3.w};
#pragma unroll
    for (int n = 0; n < 16; n++){
      float dA = exp2f(del * a2[n]);
      h[n] = fmaf(dA, h[n], dbx * bb[n]);
    }
  }
  float* hp = &hend[((size_t)c*EDc + e0 + tid)*16];
#pragma unroll
  for (int n = 0; n < 16; n += 4)
    *(float4*)&hp[n] = make_float4(h[n], h[n+1], h[n+2], h[n+3]);
  dsum[c*EDc + e0 + tid] = ds;
}

__global__ __launch_bounds__(256) void scan_p2(
  const float* __restrict__ hend, const float* __restrict__ dsum,
  const float* __restrict__ A_log, float* __restrict__ hin)
{
  int g = blockIdx.x*256 + threadIdx.x;
  int e = g >> 4;
  float a2 = -__expf(A_log[g]) * LOG2E;
  float h = 0.f;
  for (int c = 0; c < SNCH; c++){
    hin[(size_t)c*EDc*Ns + g] = h;
    float P = exp2f(a2 * dsum[c*EDc + e]);
    h = fmaf(P, h, hend[(size_t)c*EDc*Ns + g]);
  }
}

__global__ __launch_bounds__(256) void scan_p3(
  const u16* __restrict__ delta, const u16* __restrict__ xc,
  const float* __restrict__ xp,  const u16* __restrict__ xzb,
  const float* __restrict__ A_log, const float* __restrict__ D_skip,
  const float* __restrict__ hin,   u16* __restrict__ y2)
{
  __shared__ u16 sdel[SCH*256], sxc[SCH*256], sz[SCH*256];
  __shared__ float sB[SCH*16], sC[SCH*16];
  int tid = threadIdx.x;
  int e0 = blockIdx.x*256, c = blockIdx.y, t0 = c*SCH;
#pragma unroll
  for (int i = 0; i < 4; i++){
    int f = (i*256+tid)*8;
    int t = f >> 8, e = f & 255;
    gload16(&delta[(size_t)(t0+t)*EDc + e0 + e], sdel + f);
    gload16(&xc  [(size_t)(t0+t)*EDc + e0 + e], sxc + f);
    gload16(&xzb [(size_t)(t0+t)*(2*EDc) + EDc + e0 + e], sz + f);
  }
  {
    int f0 = tid, f1 = tid + 256;
    sB[f0] = xp[(size_t)(t0 + (f0>>4))*96 + Rr + (f0&15)];
    sB[f1] = xp[(size_t)(t0 + (f1>>4))*96 + Rr + (f1&15)];
    sC[f0] = xp[(size_t)(t0 + (f0>>4))*96 + Rr + Ns + (f0&15)];
    sC[f1] = xp[(size_t)(t0 + (f1>>4))*96 + Rr + Ns + (f1&15)];
  }
  float a2[16];
  {
    const float* ar = &A_log[(size_t)(e0+tid)*16];
#pragma unroll
    for (int n = 0; n < 16; n++) a2[n] = -__expf(ar[n]) * LOG2E;
  }
  float dsk = D_skip[e0 + tid];
  float h[16];
  {
    const float* hp = &hin[((size_t)c*EDc + e0 + tid)*16];
#pragma unroll
    for (int n = 0; n < 16; n += 4){
      float4 hv = *(const float4*)&hp[n];
      h[n] = hv.x; h[n+1] = hv.y; h[n+2] = hv.z; h[n+3] = hv.w;
    }
  }
  __syncthreads();
  for (int t = 0; t < SCH; t++){
    float del = b2f(sdel[t*256 + tid]);
    float xv  = b2f(sxc [t*256 + tid]);
    float zv  = b2f(sz  [t*256 + tid]);
    float dbx = del * xv;
    float4 b0 = *(const float4*)&sB[t*16];
    float4 b1 = *(const float4*)&sB[t*16+4];
    float4 b2 = *(const float4*)&sB[t*16+8];
    float4 b3 = *(const float4*)&sB[t*16+12];
    float bb[16] = {b0.x,b0.y,b0.z,b0.w, b1.x,b1.y,b1.z,b1.w,
                    b2.x,b2.y,b2.z,b2.w, b3.x,b3.y,b3.z,b3.w};
    float4 c0 = *(const float4*)&sC[t*16];
    float4 c1 = *(const float4*)&sC[t*16+4];
    float4 c2 = *(const float4*)&sC[t*16+8];
    float4 c3 = *(const float4*)&sC[t*16+12];
    float cc[16] = {c0.x,c0.y,c0.z,c0.w, c1.x,c1.y,c1.z,c1.w,
                    c2.x,c2.y,c2.z,c2.w, c3.x,c3.y,c3.z,c3.w};
    float p0 = 0.f, p1 = 0.f, p2 = 0.f, p3 = 0.f;
#pragma unroll
    for (int n = 0; n < 16; n += 4){
      float dA0 = exp2f(del * a2[n]);
      float dA1 = exp2f(del * a2[n+1]);
      float dA2 = exp2f(del * a2[n+2]);
      float dA3 = exp2f(del * a2[n+3]);
      h[n]   = fmaf(dA0, h[n],   dbx * bb[n]);
      h[n+1] = fmaf(dA1, h[n+1], dbx * bb[n+1]);
      h[n+2] = fmaf(dA2, h[n+2], dbx * bb[n+2]);
      h[n+3] = fmaf(dA3, h[n+3], dbx * bb[n+3]);
      p0 = fmaf(h[n],   cc[n],   p0);
      p1 = fmaf(h[n+1], cc[n+1], p1);
      p2 = fmaf(h[n+2], cc[n+2], p2);
      p3 = fmaf(h[n+3], cc[n+3], p3);
    }
    float p = (p0 + p1) + (p2 + p3);
    y2[(size_t)(t0+t)*EDc + e0 + tid] = bfr((p + dsk*xv) * siluf(zv));
  }
}

// ------------- router ------------------------------------------------------
__global__ __launch_bounds__(256) void route_k(
  const float* __restrict__ h2, const float* __restrict__ Wr,
  float* __restrict__ logits_out,
  int* __restrict__ cnt, int* __restrict__ bucket,
  int* __restrict__ tok_e, int* __restrict__ tok_idx, float* __restrict__ tok_w)
{
  int t = blockIdx.x, tid = threadIdx.x;
  float p[8] = {};
#pragma unroll
  for (int j = 0; j < 4; j++){
    int d = tid + j*256;
    float xv = h2[(size_t)t*Dm + d];
#pragma unroll
    for (int e = 0; e < 8; e++) p[e] += xv * Wr[e*Dm + d];
  }
#pragma unroll
  for (int e = 0; e < 8; e++)
#pragma unroll
    for (int m = 1; m < 64; m <<= 1) p[e] += __shfl_xor(p[e], m);
  __shared__ float part[4][8];
  __shared__ float lg[8];
  int lane = tid & 63, wv = tid >> 6;
  if (lane == 0)
#pragma unroll
    for (int e = 0; e < 8; e++) part[wv][e] = p[e];
  __syncthreads();
  if (tid < 8){
    float v = part[0][tid]+part[1][tid]+part[2][tid]+part[3][tid];
    lg[tid] = v;
    logits_out[(size_t)t*8 + tid] = v;
  }
  __syncthreads();
  if (tid == 0){
    float mx = lg[0];
#pragma unroll
    for (int e = 1; e < 8; e++) mx = fmaxf(mx, lg[e]);
    float ex[8], s = 0.f;
#pragma unroll
    for (int e = 0; e < 8; e++){ ex[e] = expf(lg[e] - mx); s += ex[e]; }
    float inv = 1.f / s;
    int i0 = 0; float b0 = ex[0]*inv;
#pragma unroll
    for (int e = 1; e < 8; e++){ float pe = ex[e]*inv; if (pe > b0){ b0 = pe; i0 = e; } }
    int i1 = -1; float b1 = -1e30f;
#pragma unroll
    for (int e = 0; e < 8; e++){ if (e == i0) continue; float pe = ex[e]*inv; if (pe > b1){ b1 = pe; i1 = e; } }
    int k0 = atomicAdd(&cnt[i0], 1); bucket[i0*Tn + k0] = t;
    int k1 = atomicAdd(&cnt[i1], 1); bucket[i1*Tn + k1] = t;
    tok_e[2*t] = i0;   tok_idx[2*t] = k0;   tok_w[2*t] = b0;
    tok_e[2*t+1] = i1; tok_idx[2*t+1] = k1; tok_w[2*t+1] = b1;
  }
}

// ---------- offsets + compact (expert, m-tile) map ------------------------
__global__ void prefix_k(const int* __restrict__ cnt, int* __restrict__ off,
                         int* __restrict__ tmap, int* __restrict__ ntot){
  if (threadIdx.x == 0 && blockIdx.x == 0){
    int s = 0;
    for (int e = 0; e < NEx; e++){ off[e] = s; s += cnt[e]; }
    int nt = 0;
    for (int e = 0; e < NEx; e++){
      int tiles = (cnt[e] + 127) >> 7;
      for (int tm = 0; tm < tiles; tm++) tmap[nt++] = (e << 16) | tm;
    }
    *ntot = nt;
  }
}

// ---------------- final combine (2 bf16 K-split slabs) --------------------
__global__ __launch_bounds__(256) void combine_k(float* __restrict__ out,
    const u16* __restrict__ Y, const int* __restrict__ off,
    const int* __restrict__ tok_e, const int* __restrict__ tok_idx,
    const float* __restrict__ tok_w)
{
  int t = blockIdx.x, tid = threadIdx.x;
  const size_t S2 = (size_t)(2*Tn)*Dm;
  int e0 = tok_e[2*t],   e1 = tok_e[2*t+1];
  size_t r0 = (size_t)(off[e0] + tok_idx[2*t])*Dm;
  size_t r1 = (size_t)(off[e1] + tok_idx[2*t+1])*Dm;
  float w0 = tok_w[2*t], w1 = tok_w[2*t+1];
#pragma unroll
  for (int j = 0; j < 4; j++){
    int d = tid + j*256;
    float y0 = b2f(Y[r0 + d]) + b2f(Y[S2 + r0 + d]);
    float y1 = b2f(Y[r1 + d]) + b2f(Y[S2 + r1 + d]);
    out[(size_t)t*Dm + d] += w0*y0 + w1*y1;
  }
}

extern "C" void kernel_launch(void* const* d_in, const int* in_sizes, int n_in,
                              void* d_out, int out_size, void* d_ws, size_t ws_size,
                              hipStream_t stream) {
  const float* x      = (const float*)d_in[0];
  const float* rms1_w = (const float*)d_in[1];
  const float* rms2_w = (const float*)d_in[2];
  const float* W_in   = (const float*)d_in[3];
  const float* conv_w = (const float*)d_in[4];
  const float* conv_b = (const float*)d_in[5];
  const float* W_xprj = (const float*)d_in[6];
  const float* W_dt   = (const float*)d_in[7];
  const float* b_dt   = (const float*)d_in[8];
  const float* A_log  = (const float*)d_in[9];
  const float* D_skip = (const float*)d_in[10];
  const float* W_out  = (const float*)d_in[11];
  const float* W_rt   = (const float*)d_in[12];
  const float* gate_w = (const float*)d_in[13];
  const float* up_w   = (const float*)d_in[14];
  const float* down_w = (const float*)d_in[15];

  float* out        = (float*)d_out;
  float* logits_out = out + (size_t)Tn*Dm;

  uint8_t* base = (uint8_t*)d_ws;
  size_t o = 0;
  auto alloc = [&](size_t bytes) -> void* {
    void* p = base + o;
    o = (o + bytes + 255) & ~(size_t)255;
    return p;
  };
  // ---- survivors (live through MoE phase) ----
  float* h2f   = (float*)alloc((size_t)Tn*Dm*4);
  u16*   h2b   = (u16*)  alloc((size_t)Tn*Dm*2);
  u16*   hmoe  = (u16*)  alloc((size_t)2*Tn*FFc*2);
  u16*   yslot = (u16*)  alloc((size_t)2*(2*Tn)*Dm*2);
  int*   cnt     = (int*)alloc(64);
  int*   off     = (int*)alloc(64);
  int*   ntot    = (int*)alloc(64);
  int*   tmap    = (int*)alloc(MAXTM*4 + 192);
  int*   bucket  = (int*)alloc((size_t)NEx*Tn*4);
  int*   tok_e   = (int*)alloc((size_t)2*Tn*4);
  int*   tok_idx = (int*)alloc((size_t)2*Tn*4);
  float* tok_w   = (float*)alloc((size_t)2*Tn*4);
  // ---- overlap zone: mamba-phase buffers also host bf16 MoE weights ----
  size_t oz = o;
  u16*   xzb   = (u16*)  alloc((size_t)Tn*2*EDc*2);
  u16*   delta = (u16*)  alloc((size_t)Tn*EDc*2);
  u16*   xc    = (u16*)  alloc((size_t)Tn*EDc*2);
  u16*   y2    = (u16*)  alloc((size_t)Tn*EDc*2);
  u16*   h1b   = (u16*)  alloc((size_t)Tn*Dm*2);
  u16*   dtA   = (u16*)  alloc((size_t)Tn*Rr*2);
  float* xp    = (float*)alloc((size_t)Tn*96*4);
  float* xp_part=(float*)alloc((size_t)4*Tn*96*4);
  float* hend  = (float*)alloc((size_t)SNCH*EDc*Ns*4);
  float* hin   = (float*)alloc((size_t)SNCH*EDc*Ns*4);
  float* dsum  = (float*)alloc((size_t)SNCH*EDc*4);
  // W_out K-split partials alias over xzb+delta+xc (dead by then)
  float* wpart = (float*)xzb;
  // MoE bf16 weights overlay the dead mamba buffers
  u16* wgate = (u16*)(base + oz);
  u16* wup   = wgate + (size_t)NEx*FFc*Dm;
  u16* wdown = wup   + (size_t)NEx*FFc*Dm;
  // mamba bf16 weights overlay the dead-until-MoE survivors
  u16* wbin  = (u16*)yslot;
  u16* wbout = wbin + (size_t)2*EDc*Dm;
  u16* wxp   = (u16*)hmoe;
  u16* wdt   = wxp + (size_t)96*EDc;

  // 0) convert all four mamba weights to bf16 in ONE launch (4 f4/thread)
  f2bm_k<<<1616, 256, 0, stream>>>(W_in, wbin, W_out, wbout, W_xprj, wxp, W_dt, wdt);
  // 1) rmsnorm 1 -> h1b
  rmsnorm_k<<<Tn, 256, 0, stream>>>(x, rms1_w, h1b);
  // 2) xz = h1 @ W_in^T -> bf16  (grid x=n-tiles, y=m-tiles)
  gemm_bb<0,1><<<dim3(32,16,1), 512, 0, stream>>>(h1b, Dm, wbin, Dm, xzb, 2*EDc, Tn, 2*EDc, Dm, nullptr);
  // 3) conv + silu -> xc
  conv_k<<<(Tn*EDc)/256, 256, 0, stream>>>(xzb, conv_w, conv_b, xc);
  // 4) xp = xc @ W_xproj^T, K-split x4, then reduce (+ dtA)
  gemm_bb<0,0><<<dim3(1,16,4), 512, 0, stream>>>(xc, EDc, wxp, EDc, xp_part, 96, Tn, 96, EDc/4, nullptr);
  xp_red<<<(Tn*96)/256, 256, 0, stream>>>(xp_part, xp, dtA);
  // 5) delta = softplus(dtA @ W_dt^T + b_dt) -> bf16
  gemm_bb<1,1><<<dim3(16,16,1), 512, 0, stream>>>(dtA, Rr, wdt, Rr, delta, EDc, Tn, EDc, Rr, b_dt);
  // 6) chunked parallel scan -> y2
  scan_p1<<<dim3(EDc/256, SNCH), 256, 0, stream>>>(delta, xc, xp, A_log, hend, dsum);
  scan_p2<<<EDc*Ns/256, 256, 0, stream>>>(hend, dsum, A_log, hin);
  scan_p3<<<dim3(EDc/256, SNCH), 256, 0, stream>>>(delta, xc, xp, xzb, A_log, D_skip, hin, y2);
  // 7) y2 @ W_out^T, K-split x4 -> fp32 partials
  gemm_bb<0,0><<<dim3(8,16,4), 512, 0, stream>>>(y2, EDc, wbout, EDc, wpart, Dm, Tn, Dm, EDc/4, nullptr);
  // 8) fused: out = x + sum(partials); rmsnorm -> h2b + h2f (+ cnt zeroing)
  rms2red_k<<<Tn, 256, 0, stream>>>(x, wpart, rms2_w, out, h2f, h2b, cnt);
  // 9) MoE weights -> bf16 (overlay zone), 4 f4/thread
  f2b3_k<<<3*((NEx*FFc*Dm/4)/1024), 256, 0, stream>>>(gate_w, up_w, down_w, wgate, wup, wdown);
  // 10) routing (cnt already zeroed by rms2red_k)
  route_k<<<Tn, 256, 0, stream>>>(h2f, W_rt, logits_out, cnt, bucket, tok_e, tok_idx, tok_w);
  prefix_k<<<1, 64, 0, stream>>>(cnt, off, tmap, ntot);
  // 11) expert gate/up (grid x=n-tiles, y=compact tiles)
  gateup8<<<dim3(16, MAXTM), 512, 0, stream>>>(h2b, wgate, wup, cnt, off, bucket, tmap, ntot, hmoe);
  // 12) expert down (grid x=n-tiles, y=compact tiles, z=K-half)
  down8<<<dim3(8, MAXTM, 2), 512, 0, stream>>>(hmoe, wdown, cnt, off, tmap, ntot, yslot);
  // 13) combine
  combine_k<<<Tn, 256, 0, stream>>>(out, yslot, off, tok_e, tok_idx, tok_w);
}